// Round 14
// baseline (336.690 us; speedup 1.0000x reference)
//
#include <hip/hip_runtime.h>
#include <hip/hip_fp16.h>
#include <math.h>

// GCN encoder, N=100000, E=1600000, C_IN=32, C_H=C_OUT=64, G=64.
// CSR build via two-level LDS counting sort (NO global atomics).
// em weight = ew*dis[dst]; dis[src] folded into features.
// R12: TRANSFORM-FIRST (agg(h)W == agg(hW)): tiny GEMMs + lean agg.
// R13: contiguous node chunks per wave + windowed edge-meta staging.
// R15: NB 256->1024. R18: clean/tail split batches.
// R20: agg nodes/wave 8->4 (grid-granularity occupancy win).
// R21: PBLK 2048 + vectorized bhist/bpart.
// R22: 4-threads/node transform GEMMs (o[16], ~35 regs, lottery-proof,
// grid 1563). 335us best; top-5 all harness fills now.
// R23: (1) agg nodes/wave 4->2: grid 6250->12500. Static occupancy is
// 100% (VGPR32/4KB LDS = 8 blocks/CU) but measured 60% - batch-boundary
// smearing (3 fill-batches of variable-duration blocks). Shorter blocks
// x2 grid = finer backfill. (2) k_bbase folded into k_bpart prologue
// (per-block 1024-entry LDS scan of btot; block 0 writes bbase[] for
// k_bucket + rowptr[n]=e): -1 dispatch.

#define NB   1024       // dst buckets (128 nodes each; supports N < 131072)
#define BSH  7          // log2(nodes per bucket)
#define BMASK 127
#define BN   128        // nodes per bucket
#define PBLK 2048       // partition blocks (8 blocks/CU)
#define FIXP_SCALE 1048576.0f   // 2^20
#define FIXP_MASK  ((1ULL << 40) - 1)

__device__ __forceinline__ int lower_bound_i(const int* __restrict__ a, int n, int v) {
    int lo = 0, hi = n;
    while (lo < hi) {
        int m = (lo + hi) >> 1;
        if (a[m] < v) lo = m + 1; else hi = m;
    }
    return lo;
}

// A1: per-block histogram over NB dst-buckets (LDS atomics only).
// 4 edges/thread via int4 (chunk aligned to 4 -> 16B-aligned loads).
__global__ __launch_bounds__(256) void k_bhist(const int* __restrict__ dst,
                                               int* __restrict__ hcnt, int e) {
    __shared__ int hist[NB];
    int tid = threadIdx.x, blk = blockIdx.x;
#pragma unroll
    for (int b = 0; b < NB / 256; ++b) hist[tid + 256 * b] = 0;
    __syncthreads();
    int chunk = (((e + PBLK - 1) / PBLK) + 3) & ~3;
    int lo = blk * chunk, hi = min(e, lo + chunk);
    for (int i = lo + tid * 4; i < hi; i += 1024) {
        if (i + 4 <= hi) {
            int4 d4 = *(const int4*)(dst + i);
            atomicAdd(&hist[d4.x >> BSH], 1);
            atomicAdd(&hist[d4.y >> BSH], 1);
            atomicAdd(&hist[d4.z >> BSH], 1);
            atomicAdd(&hist[d4.w >> BSH], 1);
        } else {
            for (int j = i; j < hi; ++j) atomicAdd(&hist[dst[j] >> BSH], 1);
        }
    }
    __syncthreads();
#pragma unroll
    for (int b = 0; b < NB / 256; ++b) {
        int bb = tid + 256 * b;
        hcnt[bb * PBLK + blk] = hist[bb];   // [bucket][block] layout
    }
}

// A2a: per-bucket exclusive scan across the PBLK block-counts (in place) + totals
__global__ __launch_bounds__(256) void k_bscan(int* __restrict__ hcnt,
                                               int* __restrict__ btot) {
    __shared__ int s[256];
    int b = blockIdx.x, tid = threadIdx.x;
    int* row = hcnt + b * PBLK;
    int a[8];
    int tsum = 0;
#pragma unroll
    for (int j = 0; j < 8; ++j) { a[j] = row[8 * tid + j]; tsum += a[j]; }
    s[tid] = tsum;
    __syncthreads();
    for (int off = 1; off < 256; off <<= 1) {
        int t = (tid >= off) ? s[tid - off] : 0;
        __syncthreads();
        s[tid] += t;
        __syncthreads();
    }
    int ex = s[tid] - tsum;
#pragma unroll
    for (int j = 0; j < 8; ++j) { row[8 * tid + j] = ex; ex += a[j]; }
    if (tid == 255) btot[b] = s[255];
}

// A3 (R23: k_bbase folded in): partition edges into buckets; per-block
// prologue re-derives bucket bases from btot via LDS scan; block 0 also
// writes bbase[] (for k_bucket) and rowptr[n]=e. pos from LDS cursor.
// 4 edges/thread: int4 dst + int4 src + float4 ew issued up front.
__global__ __launch_bounds__(256) void k_bpart(const int* __restrict__ src,
                                               const int* __restrict__ dst,
                                               const float* __restrict__ ew,
                                               const int* __restrict__ hcnt,
                                               const int* __restrict__ btot,
                                               int* __restrict__ bbase,
                                               int* __restrict__ rowptr,
                                               int2* __restrict__ bedge,
                                               int e, int n) {
    __shared__ int cur[NB];
    __shared__ int s[256];
    int tid = threadIdx.x, blk = blockIdx.x;
    // bucket-base scan (old k_bbase, per block; 4 entries/thread)
    int a0 = btot[4 * tid], a1 = btot[4 * tid + 1],
        a2 = btot[4 * tid + 2], a3 = btot[4 * tid + 3];
    int tsum = a0 + a1 + a2 + a3;
    s[tid] = tsum;
    __syncthreads();
    for (int off = 1; off < 256; off <<= 1) {
        int t = (tid >= off) ? s[tid - off] : 0;
        __syncthreads();
        s[tid] += t;
        __syncthreads();
    }
    int ex = s[tid] - tsum;
    int b0 = ex, b1 = ex + a0, b2 = ex + a0 + a1, b3 = ex + a0 + a1 + a2;
    cur[4 * tid + 0] = b0 + hcnt[(4 * tid + 0) * PBLK + blk];
    cur[4 * tid + 1] = b1 + hcnt[(4 * tid + 1) * PBLK + blk];
    cur[4 * tid + 2] = b2 + hcnt[(4 * tid + 2) * PBLK + blk];
    cur[4 * tid + 3] = b3 + hcnt[(4 * tid + 3) * PBLK + blk];
    if (blk == 0) {                            // publish bases for k_bucket
        bbase[4 * tid + 0] = b0;
        bbase[4 * tid + 1] = b1;
        bbase[4 * tid + 2] = b2;
        bbase[4 * tid + 3] = b3;
        if (tid == 255) bbase[NB] = s[255];    // == e
        if (tid == 0) rowptr[n] = e;
    }
    __syncthreads();
    int chunk = (((e + PBLK - 1) / PBLK) + 3) & ~3;
    int lo = blk * chunk, hi = min(e, lo + chunk);
    for (int i = lo + tid * 4; i < hi; i += 1024) {
        if (i + 4 <= hi) {
            int4 d4 = *(const int4*)(dst + i);
            int4 s4 = *(const int4*)(src + i);
            float4 w4 = *(const float4*)(ew + i);
            int p0 = atomicAdd(&cur[d4.x >> BSH], 1);
            int p1 = atomicAdd(&cur[d4.y >> BSH], 1);
            int p2 = atomicAdd(&cur[d4.z >> BSH], 1);
            int p3 = atomicAdd(&cur[d4.w >> BSH], 1);
            bedge[p0] = make_int2(s4.x | ((d4.x & BMASK) << 17), __float_as_int(w4.x));
            bedge[p1] = make_int2(s4.y | ((d4.y & BMASK) << 17), __float_as_int(w4.y));
            bedge[p2] = make_int2(s4.z | ((d4.z & BMASK) << 17), __float_as_int(w4.z));
            bedge[p3] = make_int2(s4.w | ((d4.w & BMASK) << 17), __float_as_int(w4.w));
        } else {
            for (int j = i; j < hi; ++j) {
                int d = dst[j];
                int pos = atomicAdd(&cur[d >> BSH], 1);
                bedge[pos] = make_int2(src[j] | ((d & BMASK) << 17),
                                       __float_as_int(ew[j]));
            }
        }
    }
}

// B: per-bucket (BN=128 nodes): LDS packed cnt + fixp sum(ew) -> dis,
// rowptr, then scatter (src, ew*dis[d]) grouped per node into em.
// Fused hs = fp16(dis*x) for this bucket's nodes. No global atomics.
__global__ __launch_bounds__(256) void k_bucket(const int2* __restrict__ bedge,
                                                const int* __restrict__ bbase,
                                                float* __restrict__ dis,
                                                int* __restrict__ rowptr,
                                                int2* __restrict__ em,
                                                const float* __restrict__ x,
                                                __half* __restrict__ hs, int n) {
    __shared__ unsigned long long pk[BN];
    __shared__ int cnt[BN];
    __shared__ int scn[BN];
    __shared__ float sdis[BN];
    __shared__ int cur[BN];
    int b = blockIdx.x, tid = threadIdx.x;
    int e0 = bbase[b], e1 = bbase[b + 1];
    if (tid < BN) pk[tid] = 0ULL;
    __syncthreads();
    for (int i = e0 + tid; i < e1; i += 256) {
        int2 v = bedge[i];
        int dlo = (v.x >> 17) & BMASK;
        unsigned long long p =
            (1ULL << 40) | (unsigned long long)(__int_as_float(v.y) * FIXP_SCALE);
        atomicAdd(&pk[dlo], p);                          // LDS atomic
    }
    __syncthreads();
    if (tid < BN) {
        unsigned long long v = pk[tid];
        int c = (int)(v >> 40);
        cnt[tid] = c; scn[tid] = c;
        sdis[tid] = rsqrtf(1.0f + (float)(v & FIXP_MASK) * (1.0f / FIXP_SCALE));
    }
    __syncthreads();
    // BN-entry inclusive scan (all threads hit the barriers)
    for (int off = 1; off < BN; off <<= 1) {
        int v0 = (tid >= off && tid < BN) ? scn[tid - off] : 0;
        __syncthreads();
        if (tid < BN) scn[tid] += v0;
        __syncthreads();
    }
    if (tid < BN) {
        int rb = e0 + scn[tid] - cnt[tid];               // exclusive
        cur[tid] = rb;
        int node = (b << BSH) + tid;
        if (node < n) { rowptr[node] = rb; dis[node] = sdis[tid]; }
    }
    __syncthreads();
    for (int i = e0 + tid; i < e1; i += 256) {
        int2 v = bedge[i];
        int dlo = (v.x >> 17) & BMASK;
        int pos = atomicAdd(&cur[dlo], 1);               // LDS atomic
        float w = __int_as_float(v.y) * sdis[dlo];
        em[pos] = make_int2(v.x & 0x1FFFF, __float_as_int(w));
    }
    // fused layer-1 pre-scale: hs = fp16(dis * x) for nodes of this bucket
    int nodebase = b << BSH;
    int nloc = n - nodebase; if (nloc > BN) nloc = BN;
    if (nloc > 0) {
        const float2* x2 = (const float2*)(x + (size_t)nodebase * 32);
        __half2* hs2 = (__half2*)(hs + (size_t)nodebase * 32);
        int total2 = nloc * 16;                    // 16 float2 per 32-ch row
        for (int i = tid; i < total2; i += 256) {
            float d = sdis[i >> 4];
            float2 v = x2[i];
            hs2[i] = __float22half2_rn(make_float2(v.x * d, v.y * d));
        }
    }
}

__device__ __forceinline__ float2 cvt_pair(unsigned int u) {
    __half2 h2 = *(__half2*)&u;
    return __half22float2(h2);
}

// R23: pure 32-ch aggregate, 4ch/lane, 16-edge units (2 slots) with
// clean/tail split; 2 NODES PER WAVE (finer blocks -> smoother occ).
// y0 = sum_e w_e hs[src] + di*hs[node].
__global__ __launch_bounds__(256, 4) void k_agg32(const __half* __restrict__ hs,
                                                  const int2* __restrict__ em,
                                                  const int* __restrict__ rowptr,
                                                  const float* __restrict__ dis,
                                                  __half* __restrict__ y0, int n) {
    __shared__ __align__(8) int2 sme[4][128];
    int lane = threadIdx.x & 63, wv = threadIdx.x >> 6;
    int c = lane & 7, oct = lane >> 3;
    const uint2* h64 = (const uint2*)hs;      // 8 uint2 per 32-ch row
    int wid = (blockIdx.x * blockDim.x + threadIdx.x) >> 6;
    int n0 = wid * 2;
    if (n0 >= n) return;
    int cnt = min(2, n - n0);
    int rp = 0;
    if (lane <= cnt) rp = rowptr[n0 + lane];
    int hiw = __shfl(rp, cnt, 64);            // end of wave's edge range
    int wlo = 0, whi = 0;                     // staged window [wlo, whi)
    for (int k = 0; k < cnt; ++k) {
        int node = n0 + k;
        int lo = __shfl(rp, k, 64), hi = __shfl(rp, k + 1, 64);
        float2 a0 = make_float2(0.0f, 0.0f), a1 = make_float2(0.0f, 0.0f);
        if (oct == 0) {
            float di = dis[node];
            uint2 sh = h64[(unsigned)(node * 8 + c)];
            float2 f0 = cvt_pair(sh.x), f1 = cvt_pair(sh.y);
            a0.x = di * f0.x; a0.y = di * f0.y;          // self: di^2*x = di*hs
            a1.x = di * f1.x; a1.y = di * f1.y;
        }
        int idx = lo;
        while (idx < hi) {
            if (idx >= whi) {                 // refill (wave-uniform)
                int i0 = idx + lane;
                if (i0 < hiw) sme[wv][lane] = em[i0];
                int i1 = i0 + 64;
                if (i1 < hiw) sme[wv][lane + 64] = em[i1];
                wlo = idx; whi = idx + 128;
            }
            int base = idx - wlo;
            int take = min(hi, whi) - idx;    // 1..128 edges this pass
            int g = 0;
            // clean 16-edge batches: no predication, no clamped dups
            for (; g + 16 <= take; g += 16) {
                int2 ev[2]; uint2 hv[2];
#pragma unroll
                for (int t = 0; t < 2; ++t)
                    ev[t] = sme[wv][base + g + 8 * t + oct];      // 8-way bcast
#pragma unroll
                for (int t = 0; t < 2; ++t)
                    hv[t] = h64[(unsigned)(ev[t].x * 8 + c)];
#pragma unroll
                for (int t = 0; t < 2; ++t) {
                    float ww = __int_as_float(ev[t].y);
                    float2 f0 = cvt_pair(hv[t].x), f1 = cvt_pair(hv[t].y);
                    a0.x = fmaf(ww, f0.x, a0.x);
                    a0.y = fmaf(ww, f0.y, a0.y);
                    a1.x = fmaf(ww, f1.x, a1.x);
                    a1.y = fmaf(ww, f1.y, a1.y);
                }
            }
            if (g < take) {                   // predicated tail (<=15 edges)
                int2 ev[2]; uint2 hv[2]; int pr[2];
#pragma unroll
                for (int t = 0; t < 2; ++t) {
                    int p = g + 8 * t + oct;
                    pr[t] = p < take;
                    int pc = pr[t] ? p : 0;               // clamp: stay in window
                    ev[t] = sme[wv][base + pc];
                }
#pragma unroll
                for (int t = 0; t < 2; ++t)
                    hv[t] = h64[(unsigned)(ev[t].x * 8 + c)];
#pragma unroll
                for (int t = 0; t < 2; ++t) {
                    float ww = pr[t] ? __int_as_float(ev[t].y) : 0.0f;
                    float2 f0 = cvt_pair(hv[t].x), f1 = cvt_pair(hv[t].y);
                    a0.x = fmaf(ww, f0.x, a0.x);
                    a0.y = fmaf(ww, f0.y, a0.y);
                    a1.x = fmaf(ww, f1.x, a1.x);
                    a1.y = fmaf(ww, f1.y, a1.y);
                }
            }
            idx += take;
        }
        // reduce across octs
        a0.x += __shfl_down(a0.x, 32, 64); a0.y += __shfl_down(a0.y, 32, 64);
        a1.x += __shfl_down(a1.x, 32, 64); a1.y += __shfl_down(a1.y, 32, 64);
        a0.x += __shfl_down(a0.x, 16, 64); a0.y += __shfl_down(a0.y, 16, 64);
        a1.x += __shfl_down(a1.x, 16, 64); a1.y += __shfl_down(a1.y, 16, 64);
        a0.x += __shfl_down(a0.x, 8, 64);  a0.y += __shfl_down(a0.y, 8, 64);
        a1.x += __shfl_down(a1.x, 8, 64);  a1.y += __shfl_down(a1.y, 8, 64);
        if (oct == 0) {
            uint2 o;
            __half2 p0 = __float22half2_rn(make_float2(a0.x, a0.y));
            __half2 p1 = __float22half2_rn(make_float2(a1.x, a1.y));
            o.x = *(unsigned int*)&p0; o.y = *(unsigned int*)&p1;
            ((uint2*)y0)[(size_t)node * 8 + c] = o;
        }
    }
}

// R22: h1' = silu(y0 @ W1 + b1) * dis.  4 THREADS PER NODE (q = 16
// outputs each); o[16], ~35 live regs (lottery-proof), grid 1563.
__global__ __launch_bounds__(256, 4) void k_mm32act(const __half* __restrict__ y0,
                                                    const float* __restrict__ W,
                                                    const float* __restrict__ bias,
                                                    const float* __restrict__ dis,
                                                    __half* __restrict__ out, int n) {
    __shared__ __align__(16) float sw[32 * 64 + 64];
#pragma unroll
    for (int i = 0; i < 8; ++i)
        sw[threadIdx.x + 256 * i] = W[threadIdx.x + 256 * i];
    if (threadIdx.x < 64) sw[2048 + threadIdx.x] = bias[threadIdx.x];
    __syncthreads();
    int idx = blockIdx.x * 256 + threadIdx.x;
    int node = idx >> 2, q = idx & 3;
    if (node >= n) return;
    const uint4* yrow = (const uint4*)(y0 + (size_t)node * 32);
    float o[16];
#pragma unroll
    for (int j = 0; j < 16; ++j) o[j] = sw[2048 + q * 16 + j];
#pragma unroll
    for (int kb = 0; kb < 2; ++kb) {           // 2 chunks of 16 channels
        uint4 ya = yrow[2 * kb], yb = yrow[2 * kb + 1];
        unsigned int yw[8] = {ya.x, ya.y, ya.z, ya.w, yb.x, yb.y, yb.z, yb.w};
#pragma unroll
        for (int k2 = 0; k2 < 8; ++k2) {
            float2 yk = cvt_pair(yw[k2]);
            int k = kb * 16 + 2 * k2;
            const float4* r0 = (const float4*)&sw[k * 64 + q * 16];
            const float4* r1 = (const float4*)&sw[(k + 1) * 64 + q * 16];
#pragma unroll
            for (int j4 = 0; j4 < 4; ++j4) {
                float4 w0 = r0[j4];
                float4 w1 = r1[j4];
                o[4 * j4 + 0] = fmaf(yk.y, w1.x, fmaf(yk.x, w0.x, o[4 * j4 + 0]));
                o[4 * j4 + 1] = fmaf(yk.y, w1.y, fmaf(yk.x, w0.y, o[4 * j4 + 1]));
                o[4 * j4 + 2] = fmaf(yk.y, w1.z, fmaf(yk.x, w0.z, o[4 * j4 + 2]));
                o[4 * j4 + 3] = fmaf(yk.y, w1.w, fmaf(yk.x, w0.w, o[4 * j4 + 3]));
            }
        }
    }
    float dsc = dis[node];
    __half2* orow = (__half2*)(out + (size_t)node * 64 + q * 16);
#pragma unroll
    for (int j2 = 0; j2 < 8; ++j2) {
        float ox = o[2 * j2], oy = o[2 * j2 + 1];
        ox = ox / (1.0f + __expf(-ox)) * dsc;
        oy = oy / (1.0f + __expf(-oy)) * dsc;
        orow[j2] = __float22half2_rn(make_float2(ox, oy));
    }
}

// R22: z = y @ W  (N x 64 fp16 in, 64x64 fp32 W in LDS, N x 64 fp16 out).
// 4 THREADS PER NODE (q = 16 outputs each); o[16], grid 1563 = 6.1
// blocks/CU. Redundant y loads are L1/L2-absorbed.
__global__ __launch_bounds__(256, 4) void k_mm64(const __half* __restrict__ y,
                                                 const float* __restrict__ W,
                                                 __half* __restrict__ z, int n) {
    __shared__ __align__(16) float sw[64 * 64];     // 16 KB
#pragma unroll
    for (int i = 0; i < 16; ++i)
        sw[threadIdx.x + 256 * i] = W[threadIdx.x + 256 * i];
    __syncthreads();
    int idx = blockIdx.x * 256 + threadIdx.x;
    int node = idx >> 2, q = idx & 3;
    if (node >= n) return;
    const uint4* yrow = (const uint4*)(y + (size_t)node * 64);
    float o[16];
#pragma unroll
    for (int j = 0; j < 16; ++j) o[j] = 0.0f;
#pragma unroll
    for (int kb = 0; kb < 4; ++kb) {           // 4 chunks of 16 channels
        uint4 ya = yrow[2 * kb], yb = yrow[2 * kb + 1];
        unsigned int yw[8] = {ya.x, ya.y, ya.z, ya.w, yb.x, yb.y, yb.z, yb.w};
#pragma unroll
        for (int k2 = 0; k2 < 8; ++k2) {
            float2 yk = cvt_pair(yw[k2]);
            int k = kb * 16 + 2 * k2;
            const float4* r0 = (const float4*)&sw[k * 64 + q * 16];
            const float4* r1 = (const float4*)&sw[(k + 1) * 64 + q * 16];
#pragma unroll
            for (int j4 = 0; j4 < 4; ++j4) {
                float4 w0 = r0[j4];
                float4 w1 = r1[j4];
                o[4 * j4 + 0] = fmaf(yk.y, w1.x, fmaf(yk.x, w0.x, o[4 * j4 + 0]));
                o[4 * j4 + 1] = fmaf(yk.y, w1.y, fmaf(yk.x, w0.y, o[4 * j4 + 1]));
                o[4 * j4 + 2] = fmaf(yk.y, w1.z, fmaf(yk.x, w0.z, o[4 * j4 + 2]));
                o[4 * j4 + 3] = fmaf(yk.y, w1.w, fmaf(yk.x, w0.w, o[4 * j4 + 3]));
            }
        }
    }
    __half2* zrow = (__half2*)(z + (size_t)node * 64 + q * 16);
#pragma unroll
    for (int j2 = 0; j2 < 8; ++j2)
        zrow[j2] = __float22half2_rn(make_float2(o[2 * j2], o[2 * j2 + 1]));
}

// R23: lean 64-ch aggregate, 4ch/lane, 16-edge units (4 slots) with
// clean/tail split; 2 NODES PER WAVE (grid 12500, smoother occupancy).
// out = [di*] silu( sum_e w_e z[src] + di*z[node] + bias ).
template <bool SCALE, typename OUT>
__global__ __launch_bounds__(256, 4) void k_agg64(const __half* __restrict__ z,
                                                  const int2* __restrict__ em,
                                                  const int* __restrict__ rowptr,
                                                  const float* __restrict__ dis,
                                                  const float* __restrict__ bias,
                                                  OUT* __restrict__ out, int n) {
    __shared__ __align__(8) int2 sme[4][128];
    int lane = threadIdx.x & 63, wv = threadIdx.x >> 6;
    int c = lane & 15, quarter = lane >> 4;
    const uint2* h64 = (const uint2*)z;       // 16 uint2 per 64-ch row
    float4 bv4 = ((const float4*)bias)[c];
    int wid = (blockIdx.x * blockDim.x + threadIdx.x) >> 6;
    int n0 = wid * 2;
    if (n0 >= n) return;
    int cnt = min(2, n - n0);
    int rp = 0;
    if (lane <= cnt) rp = rowptr[n0 + lane];
    int hiw = __shfl(rp, cnt, 64);
    int wlo = 0, whi = 0;
    for (int k = 0; k < cnt; ++k) {
        int node = n0 + k;
        int lo = __shfl(rp, k, 64), hi = __shfl(rp, k + 1, 64);
        float di = 0.0f;
        float2 a0 = make_float2(0.0f, 0.0f), a1 = make_float2(0.0f, 0.0f);
        if (quarter == 0) {
            di = dis[node];
            uint2 sh = h64[(unsigned)(node * 16 + c)];
            float2 f0 = cvt_pair(sh.x), f1 = cvt_pair(sh.y);
            a0.x = di * f0.x; a0.y = di * f0.y;          // self-loop term
            a1.x = di * f1.x; a1.y = di * f1.y;
        }
        int idx = lo;
        while (idx < hi) {
            if (idx >= whi) {                 // refill (wave-uniform)
                int i0 = idx + lane;
                if (i0 < hiw) sme[wv][lane] = em[i0];
                int i1 = i0 + 64;
                if (i1 < hiw) sme[wv][lane + 64] = em[i1];
                wlo = idx; whi = idx + 128;
            }
            int base = idx - wlo;
            int take = min(hi, whi) - idx;
            int g = 0;
            // clean 16-edge batches: no predication, no clamped dups
            for (; g + 16 <= take; g += 16) {
                int2 ev[4]; uint2 hv[4];
#pragma unroll
                for (int t = 0; t < 4; ++t)
                    ev[t] = sme[wv][base + g + 4 * t + quarter];  // 4-way bcast
#pragma unroll
                for (int t = 0; t < 4; ++t)
                    hv[t] = h64[(unsigned)(ev[t].x * 16 + c)];
#pragma unroll
                for (int t = 0; t < 4; ++t) {
                    float ww = __int_as_float(ev[t].y);
                    float2 f0 = cvt_pair(hv[t].x), f1 = cvt_pair(hv[t].y);
                    a0.x = fmaf(ww, f0.x, a0.x);
                    a0.y = fmaf(ww, f0.y, a0.y);
                    a1.x = fmaf(ww, f1.x, a1.x);
                    a1.y = fmaf(ww, f1.y, a1.y);
                }
            }
            if (g < take) {                   // predicated tail (<=15 edges)
                int2 ev[4]; uint2 hv[4]; int pr[4];
#pragma unroll
                for (int t = 0; t < 4; ++t) {
                    int p = g + 4 * t + quarter;
                    pr[t] = p < take;
                    int pc = pr[t] ? p : 0;               // clamp: stay in window
                    ev[t] = sme[wv][base + pc];
                }
#pragma unroll
                for (int t = 0; t < 4; ++t)
                    hv[t] = h64[(unsigned)(ev[t].x * 16 + c)];
#pragma unroll
                for (int t = 0; t < 4; ++t) {
                    float ww = pr[t] ? __int_as_float(ev[t].y) : 0.0f;
                    float2 f0 = cvt_pair(hv[t].x), f1 = cvt_pair(hv[t].y);
                    a0.x = fmaf(ww, f0.x, a0.x);
                    a0.y = fmaf(ww, f0.y, a0.y);
                    a1.x = fmaf(ww, f1.x, a1.x);
                    a1.y = fmaf(ww, f1.y, a1.y);
                }
            }
            idx += take;
        }
        a0.x += __shfl_down(a0.x, 32, 64); a0.y += __shfl_down(a0.y, 32, 64);
        a1.x += __shfl_down(a1.x, 32, 64); a1.y += __shfl_down(a1.y, 32, 64);
        a0.x += __shfl_down(a0.x, 16, 64); a0.y += __shfl_down(a0.y, 16, 64);
        a1.x += __shfl_down(a1.x, 16, 64); a1.y += __shfl_down(a1.y, 16, 64);
        if (quarter == 0) {
            float ox = a0.x + bv4.x, oy = a0.y + bv4.y;
            float oz = a1.x + bv4.z, ow = a1.y + bv4.w;
            ox = ox / (1.0f + __expf(-ox));
            oy = oy / (1.0f + __expf(-oy));
            oz = oz / (1.0f + __expf(-oz));
            ow = ow / (1.0f + __expf(-ow));
            if (SCALE) { ox *= di; oy *= di; oz *= di; ow *= di; }
            if (sizeof(OUT) == 2) {
                uint2 o;
                __half2 p0 = __float22half2_rn(make_float2(ox, oy));
                __half2 p1 = __float22half2_rn(make_float2(oz, ow));
                o.x = *(unsigned int*)&p0; o.y = *(unsigned int*)&p1;
                ((uint2*)out)[(size_t)node * 16 + c] = o;
            } else {
                ((float4*)out)[(size_t)node * 16 + c] = make_float4(ox, oy, oz, ow);
            }
        }
    }
}

// pool phase 1: 128-row chunks, segment-flush atomics into acc[G*64]
__global__ void k_pool_partial(const float* __restrict__ h, const int* __restrict__ batch,
                               float* __restrict__ acc, int n) {
    int c = threadIdx.x & 63, r = threadIdx.x >> 6;
    int base = blockIdx.x * 128;
    int end = base + 128; if (end > n) end = n;
    float part = 0.0f;
    int cur = -1;
    for (int i = base + r; i < end; i += 4) {
        int g = batch[i];
        if (g != cur) {
            if (cur >= 0) atomicAdd(&acc[cur * 64 + c], part);
            part = 0.0f;
            cur = g;
        }
        part += h[(size_t)i * 64 + c];
    }
    if (cur >= 0) atomicAdd(&acc[cur * 64 + c], part);
}

// pool phase 2: divide by per-graph count
__global__ void k_pool_final(const float* __restrict__ acc, const int* __restrict__ batch,
                             float* __restrict__ out, int n) {
    int idx = blockIdx.x * blockDim.x + threadIdx.x;   // G*64 threads
    int g = idx >> 6;
    int lo = lower_bound_i(batch, n, g);
    int hi = lower_bound_i(batch, n, g + 1);
    int cnt = hi - lo;
    out[idx] = acc[idx] / (float)(cnt > 0 ? cnt : 1);
}

extern "C" void kernel_launch(void* const* d_in, const int* in_sizes, int n_in,
                              void* d_out, int out_size, void* d_ws, size_t ws_size,
                              hipStream_t stream) {
    const float* x   = (const float*)d_in[0];
    const float* ew  = (const float*)d_in[1];
    const float* W1  = (const float*)d_in[2];
    const float* b1  = (const float*)d_in[3];
    const float* W2  = (const float*)d_in[4];
    const float* b2  = (const float*)d_in[5];
    const float* W3  = (const float*)d_in[6];
    const float* b3  = (const float*)d_in[7];
    const int*   eidx  = (const int*)d_in[8];
    const int*   batch = (const int*)d_in[9];
    float* out = (float*)d_out;

    const int E = in_sizes[1];       // 1,600,000
    const int N = in_sizes[9];       // 100,000 (< 131072: fits 17-bit src pack)
    const int G = 64;
    const int* src = eidx;
    const int* dst = eidx + E;

    // workspace: A/B (fp16 features) double as CSR-build scratch
    // (bedge in A: E*8B == N*64*2B exactly; hcnt/btot in B: 8MB+4KB
    // fits B's 12.8MB); C holds fp16 y0 early, then the final fp32 layer.
    char* p = (char*)d_ws;
    __half* A     = (__half*)p;                p += (size_t)N * 64 * sizeof(__half);
    __half* B     = (__half*)p;                p += (size_t)N * 64 * sizeof(__half);
    float* C      = (float*)p;                 p += (size_t)N * 64 * sizeof(float);
    float* dis    = (float*)p;                 p += (size_t)N * sizeof(float);
    int*   rowptr = (int*)p;                   p += (size_t)(N + 1) * sizeof(int);
    int*   bbase  = (int*)p;                   p += (size_t)(NB + 1) * sizeof(int);
    float* acc    = (float*)p;                 p += (size_t)G * 64 * sizeof(float);
    p = (char*)(((uintptr_t)p + 7) & ~(uintptr_t)7);
    int2*  em     = (int2*)p;                  // E entries, 8B

    int2* bedge = (int2*)A;                    // E*8B == N*64*2B
    int*  hcnt  = (int*)B;                     // NB*PBLK*4B = 8MB
    int*  btot  = (int*)B + NB * PBLK;         // NB ints

    const int BT = 256;
    const int WAVES = (N + 1) / 2;             // 50000 waves, 2 contiguous nodes each
    const int AGG_BLOCKS = (WAVES + 3) / 4;    // 12500 -> fine-grained backfill
    const int MM_BLOCKS = (4 * N + 255) / 256; // 1563, 4 threads per node

    // --- CSR build: LDS counting sort, zero global atomics ---
    k_bhist<<<PBLK, 256, 0, stream>>>(dst, hcnt, E);
    k_bscan<<<NB, 256, 0, stream>>>(hcnt, btot);
    // bbase folded into k_bpart (block 0 publishes bbase + rowptr[n])
    k_bpart<<<PBLK, 256, 0, stream>>>(src, dst, ew, hcnt, btot, bbase, rowptr,
                                      bedge, E, N);
    // k_bucket also emits hs = fp16(dis*x) into B (hcnt scratch dead here)
    k_bucket<<<NB, 256, 0, stream>>>(bedge, bbase, dis, rowptr, em, x, (__half*)B, N);

    // --- layer 1: pure 32-ch aggregate -> y0 (fp16, in C) ;
    //     h1' = silu(y0@W1+b1)*dis -> A ---
    k_agg32<<<AGG_BLOCKS, BT, 0, stream>>>((__half*)B, em, rowptr, dis, (__half*)C, N);
    k_mm32act<<<MM_BLOCKS, BT, 0, stream>>>((__half*)C, W1, b1, dis, A, N);

    // --- layer 2: z2 = y1 @ W2 -> B ; agg+bias+silu*dis -> A ---
    k_mm64<<<MM_BLOCKS, BT, 0, stream>>>(A, W2, B, N);
    k_agg64<true, __half><<<AGG_BLOCKS, BT, 0, stream>>>(B, em, rowptr, dis, b2, A, N);

    // --- layer 3: z3 = y2 @ W3 -> B ; agg+bias+silu (fp32) -> C ---
    k_mm64<<<MM_BLOCKS, BT, 0, stream>>>(A, W3, B, N);
    k_agg64<false, float><<<AGG_BLOCKS, BT, 0, stream>>>(B, em, rowptr, dis, b3, C, N);

    // --- mean pool ---
    hipMemsetAsync(acc, 0, (size_t)G * 64 * sizeof(float), stream);
    k_pool_partial<<<(N + 127) / 128, BT, 0, stream>>>(C, batch, acc, N);
    k_pool_final<<<(G * 64) / BT, BT, 0, stream>>>(acc, batch, out, N);
}

// Round 15
// 328.636 us; speedup vs baseline: 1.0245x; 1.0245x over previous
//
#include <hip/hip_runtime.h>
#include <hip/hip_fp16.h>
#include <math.h>

// GCN encoder, N=100000, E=1600000, C_IN=32, C_H=C_OUT=64, G=64.
// CSR build via two-level LDS counting sort (NO global atomics).
// em weight = ew*dis[dst]; dis[src] folded into features.
// R12: TRANSFORM-FIRST (agg(h)W == agg(hW)): tiny GEMMs + lean agg.
// R13: contiguous node chunks per wave + windowed edge-meta staging.
// R15: NB 256->1024. R18: clean/tail split batches.
// R20/R23: agg nodes/wave 8->4->2 (grid-granularity occupancy).
// R21: PBLK 2048 + vectorized bhist/bpart; bbase folded into bpart.
// R22: 4-threads/node transform GEMMs (o[16], lottery-proof). 335us.
// R23: occupancy 60->65% but duration flat - agg kernels at practical
// floor (VALU 68%, occ 65%, HBM 31%; 6 rounds of inner-loop attacks
// netted 47->42us with last three <=+-1us).
// R24: traffic trim. (1) hcnt -> u16 (counts<=~2000 fit; touched 4x:
// 32MB -> 16MB across CSR build). (2) layer-3 output fp16 into A (dead
// after mm64) + pool_partial reads half: pool input 25.6 -> 12.8MB.
// absmax est ~1e-4 (fp16 quant of h3, unbiased, averaged per graph).

#define NB   1024       // dst buckets (128 nodes each; supports N < 131072)
#define BSH  7          // log2(nodes per bucket)
#define BMASK 127
#define BN   128        // nodes per bucket
#define PBLK 2048       // partition blocks (8 blocks/CU)
#define FIXP_SCALE 1048576.0f   // 2^20
#define FIXP_MASK  ((1ULL << 40) - 1)

__device__ __forceinline__ int lower_bound_i(const int* __restrict__ a, int n, int v) {
    int lo = 0, hi = n;
    while (lo < hi) {
        int m = (lo + hi) >> 1;
        if (a[m] < v) lo = m + 1; else hi = m;
    }
    return lo;
}

// A1: per-block histogram over NB dst-buckets (LDS atomics only).
// 4 edges/thread via int4; hcnt stored as u16 (counts <= ~800).
__global__ __launch_bounds__(256) void k_bhist(const int* __restrict__ dst,
                                               unsigned short* __restrict__ hcnt,
                                               int e) {
    __shared__ int hist[NB];
    int tid = threadIdx.x, blk = blockIdx.x;
#pragma unroll
    for (int b = 0; b < NB / 256; ++b) hist[tid + 256 * b] = 0;
    __syncthreads();
    int chunk = (((e + PBLK - 1) / PBLK) + 3) & ~3;
    int lo = blk * chunk, hi = min(e, lo + chunk);
    for (int i = lo + tid * 4; i < hi; i += 1024) {
        if (i + 4 <= hi) {
            int4 d4 = *(const int4*)(dst + i);
            atomicAdd(&hist[d4.x >> BSH], 1);
            atomicAdd(&hist[d4.y >> BSH], 1);
            atomicAdd(&hist[d4.z >> BSH], 1);
            atomicAdd(&hist[d4.w >> BSH], 1);
        } else {
            for (int j = i; j < hi; ++j) atomicAdd(&hist[dst[j] >> BSH], 1);
        }
    }
    __syncthreads();
#pragma unroll
    for (int b = 0; b < NB / 256; ++b) {
        int bb = tid + 256 * b;
        hcnt[(size_t)bb * PBLK + blk] = (unsigned short)hist[bb];
    }
}

// A2a: per-bucket exclusive scan across the PBLK block-counts (in place,
// u16: prefix <= bucket total ~2000) + totals
__global__ __launch_bounds__(256) void k_bscan(unsigned short* __restrict__ hcnt,
                                               int* __restrict__ btot) {
    __shared__ int s[256];
    int b = blockIdx.x, tid = threadIdx.x;
    unsigned short* row = hcnt + (size_t)b * PBLK;
    int a[8];
    int tsum = 0;
#pragma unroll
    for (int j = 0; j < 8; ++j) { a[j] = row[8 * tid + j]; tsum += a[j]; }
    s[tid] = tsum;
    __syncthreads();
    for (int off = 1; off < 256; off <<= 1) {
        int t = (tid >= off) ? s[tid - off] : 0;
        __syncthreads();
        s[tid] += t;
        __syncthreads();
    }
    int ex = s[tid] - tsum;
#pragma unroll
    for (int j = 0; j < 8; ++j) { row[8 * tid + j] = (unsigned short)ex; ex += a[j]; }
    if (tid == 255) btot[b] = s[255];
}

// A3 (bbase folded in): partition edges into buckets; per-block prologue
// re-derives bucket bases from btot via LDS scan; block 0 also writes
// bbase[] (for k_bucket) and rowptr[n]=e. pos from LDS cursor.
// 4 edges/thread: int4 dst + int4 src + float4 ew issued up front.
__global__ __launch_bounds__(256) void k_bpart(const int* __restrict__ src,
                                               const int* __restrict__ dst,
                                               const float* __restrict__ ew,
                                               const unsigned short* __restrict__ hcnt,
                                               const int* __restrict__ btot,
                                               int* __restrict__ bbase,
                                               int* __restrict__ rowptr,
                                               int2* __restrict__ bedge,
                                               int e, int n) {
    __shared__ int cur[NB];
    __shared__ int s[256];
    int tid = threadIdx.x, blk = blockIdx.x;
    // bucket-base scan (old k_bbase, per block; 4 entries/thread)
    int a0 = btot[4 * tid], a1 = btot[4 * tid + 1],
        a2 = btot[4 * tid + 2], a3 = btot[4 * tid + 3];
    int tsum = a0 + a1 + a2 + a3;
    s[tid] = tsum;
    __syncthreads();
    for (int off = 1; off < 256; off <<= 1) {
        int t = (tid >= off) ? s[tid - off] : 0;
        __syncthreads();
        s[tid] += t;
        __syncthreads();
    }
    int ex = s[tid] - tsum;
    int b0 = ex, b1 = ex + a0, b2 = ex + a0 + a1, b3 = ex + a0 + a1 + a2;
    cur[4 * tid + 0] = b0 + hcnt[(size_t)(4 * tid + 0) * PBLK + blk];
    cur[4 * tid + 1] = b1 + hcnt[(size_t)(4 * tid + 1) * PBLK + blk];
    cur[4 * tid + 2] = b2 + hcnt[(size_t)(4 * tid + 2) * PBLK + blk];
    cur[4 * tid + 3] = b3 + hcnt[(size_t)(4 * tid + 3) * PBLK + blk];
    if (blk == 0) {                            // publish bases for k_bucket
        bbase[4 * tid + 0] = b0;
        bbase[4 * tid + 1] = b1;
        bbase[4 * tid + 2] = b2;
        bbase[4 * tid + 3] = b3;
        if (tid == 255) bbase[NB] = s[255];    // == e
        if (tid == 0) rowptr[n] = e;
    }
    __syncthreads();
    int chunk = (((e + PBLK - 1) / PBLK) + 3) & ~3;
    int lo = blk * chunk, hi = min(e, lo + chunk);
    for (int i = lo + tid * 4; i < hi; i += 1024) {
        if (i + 4 <= hi) {
            int4 d4 = *(const int4*)(dst + i);
            int4 s4 = *(const int4*)(src + i);
            float4 w4 = *(const float4*)(ew + i);
            int p0 = atomicAdd(&cur[d4.x >> BSH], 1);
            int p1 = atomicAdd(&cur[d4.y >> BSH], 1);
            int p2 = atomicAdd(&cur[d4.z >> BSH], 1);
            int p3 = atomicAdd(&cur[d4.w >> BSH], 1);
            bedge[p0] = make_int2(s4.x | ((d4.x & BMASK) << 17), __float_as_int(w4.x));
            bedge[p1] = make_int2(s4.y | ((d4.y & BMASK) << 17), __float_as_int(w4.y));
            bedge[p2] = make_int2(s4.z | ((d4.z & BMASK) << 17), __float_as_int(w4.z));
            bedge[p3] = make_int2(s4.w | ((d4.w & BMASK) << 17), __float_as_int(w4.w));
        } else {
            for (int j = i; j < hi; ++j) {
                int d = dst[j];
                int pos = atomicAdd(&cur[d >> BSH], 1);
                bedge[pos] = make_int2(src[j] | ((d & BMASK) << 17),
                                       __float_as_int(ew[j]));
            }
        }
    }
}

// B: per-bucket (BN=128 nodes): LDS packed cnt + fixp sum(ew) -> dis,
// rowptr, then scatter (src, ew*dis[d]) grouped per node into em.
// Fused hs = fp16(dis*x) for this bucket's nodes. No global atomics.
__global__ __launch_bounds__(256) void k_bucket(const int2* __restrict__ bedge,
                                                const int* __restrict__ bbase,
                                                float* __restrict__ dis,
                                                int* __restrict__ rowptr,
                                                int2* __restrict__ em,
                                                const float* __restrict__ x,
                                                __half* __restrict__ hs, int n) {
    __shared__ unsigned long long pk[BN];
    __shared__ int cnt[BN];
    __shared__ int scn[BN];
    __shared__ float sdis[BN];
    __shared__ int cur[BN];
    int b = blockIdx.x, tid = threadIdx.x;
    int e0 = bbase[b], e1 = bbase[b + 1];
    if (tid < BN) pk[tid] = 0ULL;
    __syncthreads();
    for (int i = e0 + tid; i < e1; i += 256) {
        int2 v = bedge[i];
        int dlo = (v.x >> 17) & BMASK;
        unsigned long long p =
            (1ULL << 40) | (unsigned long long)(__int_as_float(v.y) * FIXP_SCALE);
        atomicAdd(&pk[dlo], p);                          // LDS atomic
    }
    __syncthreads();
    if (tid < BN) {
        unsigned long long v = pk[tid];
        int c = (int)(v >> 40);
        cnt[tid] = c; scn[tid] = c;
        sdis[tid] = rsqrtf(1.0f + (float)(v & FIXP_MASK) * (1.0f / FIXP_SCALE));
    }
    __syncthreads();
    // BN-entry inclusive scan (all threads hit the barriers)
    for (int off = 1; off < BN; off <<= 1) {
        int v0 = (tid >= off && tid < BN) ? scn[tid - off] : 0;
        __syncthreads();
        if (tid < BN) scn[tid] += v0;
        __syncthreads();
    }
    if (tid < BN) {
        int rb = e0 + scn[tid] - cnt[tid];               // exclusive
        cur[tid] = rb;
        int node = (b << BSH) + tid;
        if (node < n) { rowptr[node] = rb; dis[node] = sdis[tid]; }
    }
    __syncthreads();
    for (int i = e0 + tid; i < e1; i += 256) {
        int2 v = bedge[i];
        int dlo = (v.x >> 17) & BMASK;
        int pos = atomicAdd(&cur[dlo], 1);               // LDS atomic
        float w = __int_as_float(v.y) * sdis[dlo];
        em[pos] = make_int2(v.x & 0x1FFFF, __float_as_int(w));
    }
    // fused layer-1 pre-scale: hs = fp16(dis * x) for nodes of this bucket
    int nodebase = b << BSH;
    int nloc = n - nodebase; if (nloc > BN) nloc = BN;
    if (nloc > 0) {
        const float2* x2 = (const float2*)(x + (size_t)nodebase * 32);
        __half2* hs2 = (__half2*)(hs + (size_t)nodebase * 32);
        int total2 = nloc * 16;                    // 16 float2 per 32-ch row
        for (int i = tid; i < total2; i += 256) {
            float d = sdis[i >> 4];
            float2 v = x2[i];
            hs2[i] = __float22half2_rn(make_float2(v.x * d, v.y * d));
        }
    }
}

__device__ __forceinline__ float2 cvt_pair(unsigned int u) {
    __half2 h2 = *(__half2*)&u;
    return __half22float2(h2);
}

// R23: pure 32-ch aggregate, 4ch/lane, 16-edge units (2 slots) with
// clean/tail split; 2 NODES PER WAVE.
// y0 = sum_e w_e hs[src] + di*hs[node].
__global__ __launch_bounds__(256, 4) void k_agg32(const __half* __restrict__ hs,
                                                  const int2* __restrict__ em,
                                                  const int* __restrict__ rowptr,
                                                  const float* __restrict__ dis,
                                                  __half* __restrict__ y0, int n) {
    __shared__ __align__(8) int2 sme[4][128];
    int lane = threadIdx.x & 63, wv = threadIdx.x >> 6;
    int c = lane & 7, oct = lane >> 3;
    const uint2* h64 = (const uint2*)hs;      // 8 uint2 per 32-ch row
    int wid = (blockIdx.x * blockDim.x + threadIdx.x) >> 6;
    int n0 = wid * 2;
    if (n0 >= n) return;
    int cnt = min(2, n - n0);
    int rp = 0;
    if (lane <= cnt) rp = rowptr[n0 + lane];
    int hiw = __shfl(rp, cnt, 64);            // end of wave's edge range
    int wlo = 0, whi = 0;                     // staged window [wlo, whi)
    for (int k = 0; k < cnt; ++k) {
        int node = n0 + k;
        int lo = __shfl(rp, k, 64), hi = __shfl(rp, k + 1, 64);
        float2 a0 = make_float2(0.0f, 0.0f), a1 = make_float2(0.0f, 0.0f);
        if (oct == 0) {
            float di = dis[node];
            uint2 sh = h64[(unsigned)(node * 8 + c)];
            float2 f0 = cvt_pair(sh.x), f1 = cvt_pair(sh.y);
            a0.x = di * f0.x; a0.y = di * f0.y;          // self: di^2*x = di*hs
            a1.x = di * f1.x; a1.y = di * f1.y;
        }
        int idx = lo;
        while (idx < hi) {
            if (idx >= whi) {                 // refill (wave-uniform)
                int i0 = idx + lane;
                if (i0 < hiw) sme[wv][lane] = em[i0];
                int i1 = i0 + 64;
                if (i1 < hiw) sme[wv][lane + 64] = em[i1];
                wlo = idx; whi = idx + 128;
            }
            int base = idx - wlo;
            int take = min(hi, whi) - idx;    // 1..128 edges this pass
            int g = 0;
            // clean 16-edge batches: no predication, no clamped dups
            for (; g + 16 <= take; g += 16) {
                int2 ev[2]; uint2 hv[2];
#pragma unroll
                for (int t = 0; t < 2; ++t)
                    ev[t] = sme[wv][base + g + 8 * t + oct];      // 8-way bcast
#pragma unroll
                for (int t = 0; t < 2; ++t)
                    hv[t] = h64[(unsigned)(ev[t].x * 8 + c)];
#pragma unroll
                for (int t = 0; t < 2; ++t) {
                    float ww = __int_as_float(ev[t].y);
                    float2 f0 = cvt_pair(hv[t].x), f1 = cvt_pair(hv[t].y);
                    a0.x = fmaf(ww, f0.x, a0.x);
                    a0.y = fmaf(ww, f0.y, a0.y);
                    a1.x = fmaf(ww, f1.x, a1.x);
                    a1.y = fmaf(ww, f1.y, a1.y);
                }
            }
            if (g < take) {                   // predicated tail (<=15 edges)
                int2 ev[2]; uint2 hv[2]; int pr[2];
#pragma unroll
                for (int t = 0; t < 2; ++t) {
                    int p = g + 8 * t + oct;
                    pr[t] = p < take;
                    int pc = pr[t] ? p : 0;               // clamp: stay in window
                    ev[t] = sme[wv][base + pc];
                }
#pragma unroll
                for (int t = 0; t < 2; ++t)
                    hv[t] = h64[(unsigned)(ev[t].x * 8 + c)];
#pragma unroll
                for (int t = 0; t < 2; ++t) {
                    float ww = pr[t] ? __int_as_float(ev[t].y) : 0.0f;
                    float2 f0 = cvt_pair(hv[t].x), f1 = cvt_pair(hv[t].y);
                    a0.x = fmaf(ww, f0.x, a0.x);
                    a0.y = fmaf(ww, f0.y, a0.y);
                    a1.x = fmaf(ww, f1.x, a1.x);
                    a1.y = fmaf(ww, f1.y, a1.y);
                }
            }
            idx += take;
        }
        // reduce across octs
        a0.x += __shfl_down(a0.x, 32, 64); a0.y += __shfl_down(a0.y, 32, 64);
        a1.x += __shfl_down(a1.x, 32, 64); a1.y += __shfl_down(a1.y, 32, 64);
        a0.x += __shfl_down(a0.x, 16, 64); a0.y += __shfl_down(a0.y, 16, 64);
        a1.x += __shfl_down(a1.x, 16, 64); a1.y += __shfl_down(a1.y, 16, 64);
        a0.x += __shfl_down(a0.x, 8, 64);  a0.y += __shfl_down(a0.y, 8, 64);
        a1.x += __shfl_down(a1.x, 8, 64);  a1.y += __shfl_down(a1.y, 8, 64);
        if (oct == 0) {
            uint2 o;
            __half2 p0 = __float22half2_rn(make_float2(a0.x, a0.y));
            __half2 p1 = __float22half2_rn(make_float2(a1.x, a1.y));
            o.x = *(unsigned int*)&p0; o.y = *(unsigned int*)&p1;
            ((uint2*)y0)[(size_t)node * 8 + c] = o;
        }
    }
}

// R22: h1' = silu(y0 @ W1 + b1) * dis.  4 THREADS PER NODE (q = 16
// outputs each); o[16], ~35 live regs (lottery-proof), grid 1563.
__global__ __launch_bounds__(256, 4) void k_mm32act(const __half* __restrict__ y0,
                                                    const float* __restrict__ W,
                                                    const float* __restrict__ bias,
                                                    const float* __restrict__ dis,
                                                    __half* __restrict__ out, int n) {
    __shared__ __align__(16) float sw[32 * 64 + 64];
#pragma unroll
    for (int i = 0; i < 8; ++i)
        sw[threadIdx.x + 256 * i] = W[threadIdx.x + 256 * i];
    if (threadIdx.x < 64) sw[2048 + threadIdx.x] = bias[threadIdx.x];
    __syncthreads();
    int idx = blockIdx.x * 256 + threadIdx.x;
    int node = idx >> 2, q = idx & 3;
    if (node >= n) return;
    const uint4* yrow = (const uint4*)(y0 + (size_t)node * 32);
    float o[16];
#pragma unroll
    for (int j = 0; j < 16; ++j) o[j] = sw[2048 + q * 16 + j];
#pragma unroll
    for (int kb = 0; kb < 2; ++kb) {           // 2 chunks of 16 channels
        uint4 ya = yrow[2 * kb], yb = yrow[2 * kb + 1];
        unsigned int yw[8] = {ya.x, ya.y, ya.z, ya.w, yb.x, yb.y, yb.z, yb.w};
#pragma unroll
        for (int k2 = 0; k2 < 8; ++k2) {
            float2 yk = cvt_pair(yw[k2]);
            int k = kb * 16 + 2 * k2;
            const float4* r0 = (const float4*)&sw[k * 64 + q * 16];
            const float4* r1 = (const float4*)&sw[(k + 1) * 64 + q * 16];
#pragma unroll
            for (int j4 = 0; j4 < 4; ++j4) {
                float4 w0 = r0[j4];
                float4 w1 = r1[j4];
                o[4 * j4 + 0] = fmaf(yk.y, w1.x, fmaf(yk.x, w0.x, o[4 * j4 + 0]));
                o[4 * j4 + 1] = fmaf(yk.y, w1.y, fmaf(yk.x, w0.y, o[4 * j4 + 1]));
                o[4 * j4 + 2] = fmaf(yk.y, w1.z, fmaf(yk.x, w0.z, o[4 * j4 + 2]));
                o[4 * j4 + 3] = fmaf(yk.y, w1.w, fmaf(yk.x, w0.w, o[4 * j4 + 3]));
            }
        }
    }
    float dsc = dis[node];
    __half2* orow = (__half2*)(out + (size_t)node * 64 + q * 16);
#pragma unroll
    for (int j2 = 0; j2 < 8; ++j2) {
        float ox = o[2 * j2], oy = o[2 * j2 + 1];
        ox = ox / (1.0f + __expf(-ox)) * dsc;
        oy = oy / (1.0f + __expf(-oy)) * dsc;
        orow[j2] = __float22half2_rn(make_float2(ox, oy));
    }
}

// R22: z = y @ W  (N x 64 fp16 in, 64x64 fp32 W in LDS, N x 64 fp16 out).
// 4 THREADS PER NODE (q = 16 outputs each); o[16], grid 1563.
__global__ __launch_bounds__(256, 4) void k_mm64(const __half* __restrict__ y,
                                                 const float* __restrict__ W,
                                                 __half* __restrict__ z, int n) {
    __shared__ __align__(16) float sw[64 * 64];     // 16 KB
#pragma unroll
    for (int i = 0; i < 16; ++i)
        sw[threadIdx.x + 256 * i] = W[threadIdx.x + 256 * i];
    __syncthreads();
    int idx = blockIdx.x * 256 + threadIdx.x;
    int node = idx >> 2, q = idx & 3;
    if (node >= n) return;
    const uint4* yrow = (const uint4*)(y + (size_t)node * 64);
    float o[16];
#pragma unroll
    for (int j = 0; j < 16; ++j) o[j] = 0.0f;
#pragma unroll
    for (int kb = 0; kb < 4; ++kb) {           // 4 chunks of 16 channels
        uint4 ya = yrow[2 * kb], yb = yrow[2 * kb + 1];
        unsigned int yw[8] = {ya.x, ya.y, ya.z, ya.w, yb.x, yb.y, yb.z, yb.w};
#pragma unroll
        for (int k2 = 0; k2 < 8; ++k2) {
            float2 yk = cvt_pair(yw[k2]);
            int k = kb * 16 + 2 * k2;
            const float4* r0 = (const float4*)&sw[k * 64 + q * 16];
            const float4* r1 = (const float4*)&sw[(k + 1) * 64 + q * 16];
#pragma unroll
            for (int j4 = 0; j4 < 4; ++j4) {
                float4 w0 = r0[j4];
                float4 w1 = r1[j4];
                o[4 * j4 + 0] = fmaf(yk.y, w1.x, fmaf(yk.x, w0.x, o[4 * j4 + 0]));
                o[4 * j4 + 1] = fmaf(yk.y, w1.y, fmaf(yk.x, w0.y, o[4 * j4 + 1]));
                o[4 * j4 + 2] = fmaf(yk.y, w1.z, fmaf(yk.x, w0.z, o[4 * j4 + 2]));
                o[4 * j4 + 3] = fmaf(yk.y, w1.w, fmaf(yk.x, w0.w, o[4 * j4 + 3]));
            }
        }
    }
    __half2* zrow = (__half2*)(z + (size_t)node * 64 + q * 16);
#pragma unroll
    for (int j2 = 0; j2 < 8; ++j2)
        zrow[j2] = __float22half2_rn(make_float2(o[2 * j2], o[2 * j2 + 1]));
}

// R23: lean 64-ch aggregate, 4ch/lane, 16-edge units (4 slots) with
// clean/tail split; 2 NODES PER WAVE.
// out = [di*] silu( sum_e w_e z[src] + di*z[node] + bias ).
template <bool SCALE, typename OUT>
__global__ __launch_bounds__(256, 4) void k_agg64(const __half* __restrict__ z,
                                                  const int2* __restrict__ em,
                                                  const int* __restrict__ rowptr,
                                                  const float* __restrict__ dis,
                                                  const float* __restrict__ bias,
                                                  OUT* __restrict__ out, int n) {
    __shared__ __align__(8) int2 sme[4][128];
    int lane = threadIdx.x & 63, wv = threadIdx.x >> 6;
    int c = lane & 15, quarter = lane >> 4;
    const uint2* h64 = (const uint2*)z;       // 16 uint2 per 64-ch row
    float4 bv4 = ((const float4*)bias)[c];
    int wid = (blockIdx.x * blockDim.x + threadIdx.x) >> 6;
    int n0 = wid * 2;
    if (n0 >= n) return;
    int cnt = min(2, n - n0);
    int rp = 0;
    if (lane <= cnt) rp = rowptr[n0 + lane];
    int hiw = __shfl(rp, cnt, 64);
    int wlo = 0, whi = 0;
    for (int k = 0; k < cnt; ++k) {
        int node = n0 + k;
        int lo = __shfl(rp, k, 64), hi = __shfl(rp, k + 1, 64);
        float di = 0.0f;
        float2 a0 = make_float2(0.0f, 0.0f), a1 = make_float2(0.0f, 0.0f);
        if (quarter == 0) {
            di = dis[node];
            uint2 sh = h64[(unsigned)(node * 16 + c)];
            float2 f0 = cvt_pair(sh.x), f1 = cvt_pair(sh.y);
            a0.x = di * f0.x; a0.y = di * f0.y;          // self-loop term
            a1.x = di * f1.x; a1.y = di * f1.y;
        }
        int idx = lo;
        while (idx < hi) {
            if (idx >= whi) {                 // refill (wave-uniform)
                int i0 = idx + lane;
                if (i0 < hiw) sme[wv][lane] = em[i0];
                int i1 = i0 + 64;
                if (i1 < hiw) sme[wv][lane + 64] = em[i1];
                wlo = idx; whi = idx + 128;
            }
            int base = idx - wlo;
            int take = min(hi, whi) - idx;
            int g = 0;
            // clean 16-edge batches: no predication, no clamped dups
            for (; g + 16 <= take; g += 16) {
                int2 ev[4]; uint2 hv[4];
#pragma unroll
                for (int t = 0; t < 4; ++t)
                    ev[t] = sme[wv][base + g + 4 * t + quarter];  // 4-way bcast
#pragma unroll
                for (int t = 0; t < 4; ++t)
                    hv[t] = h64[(unsigned)(ev[t].x * 16 + c)];
#pragma unroll
                for (int t = 0; t < 4; ++t) {
                    float ww = __int_as_float(ev[t].y);
                    float2 f0 = cvt_pair(hv[t].x), f1 = cvt_pair(hv[t].y);
                    a0.x = fmaf(ww, f0.x, a0.x);
                    a0.y = fmaf(ww, f0.y, a0.y);
                    a1.x = fmaf(ww, f1.x, a1.x);
                    a1.y = fmaf(ww, f1.y, a1.y);
                }
            }
            if (g < take) {                   // predicated tail (<=15 edges)
                int2 ev[4]; uint2 hv[4]; int pr[4];
#pragma unroll
                for (int t = 0; t < 4; ++t) {
                    int p = g + 4 * t + quarter;
                    pr[t] = p < take;
                    int pc = pr[t] ? p : 0;               // clamp: stay in window
                    ev[t] = sme[wv][base + pc];
                }
#pragma unroll
                for (int t = 0; t < 4; ++t)
                    hv[t] = h64[(unsigned)(ev[t].x * 16 + c)];
#pragma unroll
                for (int t = 0; t < 4; ++t) {
                    float ww = pr[t] ? __int_as_float(ev[t].y) : 0.0f;
                    float2 f0 = cvt_pair(hv[t].x), f1 = cvt_pair(hv[t].y);
                    a0.x = fmaf(ww, f0.x, a0.x);
                    a0.y = fmaf(ww, f0.y, a0.y);
                    a1.x = fmaf(ww, f1.x, a1.x);
                    a1.y = fmaf(ww, f1.y, a1.y);
                }
            }
            idx += take;
        }
        a0.x += __shfl_down(a0.x, 32, 64); a0.y += __shfl_down(a0.y, 32, 64);
        a1.x += __shfl_down(a1.x, 32, 64); a1.y += __shfl_down(a1.y, 32, 64);
        a0.x += __shfl_down(a0.x, 16, 64); a0.y += __shfl_down(a0.y, 16, 64);
        a1.x += __shfl_down(a1.x, 16, 64); a1.y += __shfl_down(a1.y, 16, 64);
        if (quarter == 0) {
            float ox = a0.x + bv4.x, oy = a0.y + bv4.y;
            float oz = a1.x + bv4.z, ow = a1.y + bv4.w;
            ox = ox / (1.0f + __expf(-ox));
            oy = oy / (1.0f + __expf(-oy));
            oz = oz / (1.0f + __expf(-oz));
            ow = ow / (1.0f + __expf(-ow));
            if (SCALE) { ox *= di; oy *= di; oz *= di; ow *= di; }
            if (sizeof(OUT) == 2) {
                uint2 o;
                __half2 p0 = __float22half2_rn(make_float2(ox, oy));
                __half2 p1 = __float22half2_rn(make_float2(oz, ow));
                o.x = *(unsigned int*)&p0; o.y = *(unsigned int*)&p1;
                ((uint2*)out)[(size_t)node * 16 + c] = o;
            } else {
                ((float4*)out)[(size_t)node * 16 + c] = make_float4(ox, oy, oz, ow);
            }
        }
    }
}

// pool phase 1 (R24: fp16 input): 128-row chunks, segment-flush atomics
__global__ void k_pool_partial(const __half* __restrict__ h, const int* __restrict__ batch,
                               float* __restrict__ acc, int n) {
    int c = threadIdx.x & 63, r = threadIdx.x >> 6;
    int base = blockIdx.x * 128;
    int end = base + 128; if (end > n) end = n;
    float part = 0.0f;
    int cur = -1;
    for (int i = base + r; i < end; i += 4) {
        int g = batch[i];
        if (g != cur) {
            if (cur >= 0) atomicAdd(&acc[cur * 64 + c], part);
            part = 0.0f;
            cur = g;
        }
        part += __half2float(h[(size_t)i * 64 + c]);
    }
    if (cur >= 0) atomicAdd(&acc[cur * 64 + c], part);
}

// pool phase 2: divide by per-graph count
__global__ void k_pool_final(const float* __restrict__ acc, const int* __restrict__ batch,
                             float* __restrict__ out, int n) {
    int idx = blockIdx.x * blockDim.x + threadIdx.x;   // G*64 threads
    int g = idx >> 6;
    int lo = lower_bound_i(batch, n, g);
    int hi = lower_bound_i(batch, n, g + 1);
    int cnt = hi - lo;
    out[idx] = acc[idx] / (float)(cnt > 0 ? cnt : 1);
}

extern "C" void kernel_launch(void* const* d_in, const int* in_sizes, int n_in,
                              void* d_out, int out_size, void* d_ws, size_t ws_size,
                              hipStream_t stream) {
    const float* x   = (const float*)d_in[0];
    const float* ew  = (const float*)d_in[1];
    const float* W1  = (const float*)d_in[2];
    const float* b1  = (const float*)d_in[3];
    const float* W2  = (const float*)d_in[4];
    const float* b2  = (const float*)d_in[5];
    const float* W3  = (const float*)d_in[6];
    const float* b3  = (const float*)d_in[7];
    const int*   eidx  = (const int*)d_in[8];
    const int*   batch = (const int*)d_in[9];
    float* out = (float*)d_out;

    const int E = in_sizes[1];       // 1,600,000
    const int N = in_sizes[9];       // 100,000 (< 131072: fits 17-bit src pack)
    const int G = 64;
    const int* src = eidx;
    const int* dst = eidx + E;

    // workspace: A/B (fp16 features) double as CSR-build scratch
    // (bedge in A: E*8B == N*64*2B exactly; hcnt(u16 4MB)+btot in B);
    // C holds fp16 y0 early; layer-3 out is fp16 into A (dead there).
    char* p = (char*)d_ws;
    __half* A     = (__half*)p;                p += (size_t)N * 64 * sizeof(__half);
    __half* B     = (__half*)p;                p += (size_t)N * 64 * sizeof(__half);
    float* C      = (float*)p;                 p += (size_t)N * 64 * sizeof(float);
    float* dis    = (float*)p;                 p += (size_t)N * sizeof(float);
    int*   rowptr = (int*)p;                   p += (size_t)(N + 1) * sizeof(int);
    int*   bbase  = (int*)p;                   p += (size_t)(NB + 1) * sizeof(int);
    float* acc    = (float*)p;                 p += (size_t)G * 64 * sizeof(float);
    p = (char*)(((uintptr_t)p + 7) & ~(uintptr_t)7);
    int2*  em     = (int2*)p;                  // E entries, 8B

    int2* bedge = (int2*)A;                    // E*8B == N*64*2B
    unsigned short* hcnt = (unsigned short*)B; // NB*PBLK*2B = 4MB
    int*  btot  = (int*)((char*)B + (size_t)NB * PBLK * 2);  // NB ints

    const int BT = 256;
    const int WAVES = (N + 1) / 2;             // 50000 waves, 2 contiguous nodes each
    const int AGG_BLOCKS = (WAVES + 3) / 4;    // 12500
    const int MM_BLOCKS = (4 * N + 255) / 256; // 1563, 4 threads per node

    // --- CSR build: LDS counting sort, zero global atomics ---
    k_bhist<<<PBLK, 256, 0, stream>>>(dst, hcnt, E);
    k_bscan<<<NB, 256, 0, stream>>>(hcnt, btot);
    // bbase folded into k_bpart (block 0 publishes bbase + rowptr[n])
    k_bpart<<<PBLK, 256, 0, stream>>>(src, dst, ew, hcnt, btot, bbase, rowptr,
                                      bedge, E, N);
    // k_bucket also emits hs = fp16(dis*x) into B (hcnt scratch dead here)
    k_bucket<<<NB, 256, 0, stream>>>(bedge, bbase, dis, rowptr, em, x, (__half*)B, N);

    // --- layer 1: pure 32-ch aggregate -> y0 (fp16, in C) ;
    //     h1' = silu(y0@W1+b1)*dis -> A ---
    k_agg32<<<AGG_BLOCKS, BT, 0, stream>>>((__half*)B, em, rowptr, dis, (__half*)C, N);
    k_mm32act<<<MM_BLOCKS, BT, 0, stream>>>((__half*)C, W1, b1, dis, A, N);

    // --- layer 2: z2 = y1 @ W2 -> B ; agg+bias+silu*dis -> A ---
    k_mm64<<<MM_BLOCKS, BT, 0, stream>>>(A, W2, B, N);
    k_agg64<true, __half><<<AGG_BLOCKS, BT, 0, stream>>>(B, em, rowptr, dis, b2, A, N);

    // --- layer 3: z3 = y2 @ W3 -> B ; agg+bias+silu (fp16) -> A ---
    // (A is dead once mm64 has consumed it; fp16 halves pool input traffic)
    k_mm64<<<MM_BLOCKS, BT, 0, stream>>>(A, W3, B, N);
    k_agg64<false, __half><<<AGG_BLOCKS, BT, 0, stream>>>(B, em, rowptr, dis, b3, A, N);

    // --- mean pool (fp16 input) ---
    hipMemsetAsync(acc, 0, (size_t)G * 64 * sizeof(float), stream);
    k_pool_partial<<<(N + 127) / 128, BT, 0, stream>>>(A, batch, acc, N);
    k_pool_final<<<(G * 64) / BT, BT, 0, stream>>>(acc, batch, out, N);
}

// Round 16
// 327.508 us; speedup vs baseline: 1.0280x; 1.0034x over previous
//
#include <hip/hip_runtime.h>
#include <hip/hip_fp16.h>
#include <math.h>

// GCN encoder, N=100000, E=1600000, C_IN=32, C_H=C_OUT=64, G=64.
// CSR build via two-level LDS counting sort (NO global atomics).
// em weight = ew*dis[dst]; dis[src] folded into features.
// R12: TRANSFORM-FIRST (agg(h)W == agg(hW)): tiny GEMMs + lean agg.
// R13: contiguous node chunks per wave + windowed edge-meta staging.
// R15: NB 256->1024. R18: clean/tail split batches.
// R20/R23: agg nodes/wave 8->4->2 (grid-granularity occupancy).
// R21: PBLK 2048 + vectorized bhist/bpart; bbase folded into bpart.
// R22: 4-threads/node transform GEMMs (o[16], lottery-proof).
// R24: hcnt u16 (CSR traffic -16MB); layer-3 fp16 + fp16 pool input
// (-12.8MB). 328.6us best; top-5 all harness fills.
// R25: packed-math polish. agg inner accumulators/features as
// ext_vector_type(2) float so the backend can emit v_pk_fma_f32
// (2 fp32 FMA per inst; CDNA4) in the hottest loop - pure codegen
// change, everything else frozen. If neutral, kernels are at their
// joint practical roofline (agg64: VALU 68%/occ 65%/HBM 31%, six
// structural attacks all +-1us).

#define NB   1024       // dst buckets (128 nodes each; supports N < 131072)
#define BSH  7          // log2(nodes per bucket)
#define BMASK 127
#define BN   128        // nodes per bucket
#define PBLK 2048       // partition blocks (8 blocks/CU)
#define FIXP_SCALE 1048576.0f   // 2^20
#define FIXP_MASK  ((1ULL << 40) - 1)

typedef float v2f __attribute__((ext_vector_type(2)));

__device__ __forceinline__ int lower_bound_i(const int* __restrict__ a, int n, int v) {
    int lo = 0, hi = n;
    while (lo < hi) {
        int m = (lo + hi) >> 1;
        if (a[m] < v) lo = m + 1; else hi = m;
    }
    return lo;
}

// A1: per-block histogram over NB dst-buckets (LDS atomics only).
// 4 edges/thread via int4; hcnt stored as u16 (counts <= ~800).
__global__ __launch_bounds__(256) void k_bhist(const int* __restrict__ dst,
                                               unsigned short* __restrict__ hcnt,
                                               int e) {
    __shared__ int hist[NB];
    int tid = threadIdx.x, blk = blockIdx.x;
#pragma unroll
    for (int b = 0; b < NB / 256; ++b) hist[tid + 256 * b] = 0;
    __syncthreads();
    int chunk = (((e + PBLK - 1) / PBLK) + 3) & ~3;
    int lo = blk * chunk, hi = min(e, lo + chunk);
    for (int i = lo + tid * 4; i < hi; i += 1024) {
        if (i + 4 <= hi) {
            int4 d4 = *(const int4*)(dst + i);
            atomicAdd(&hist[d4.x >> BSH], 1);
            atomicAdd(&hist[d4.y >> BSH], 1);
            atomicAdd(&hist[d4.z >> BSH], 1);
            atomicAdd(&hist[d4.w >> BSH], 1);
        } else {
            for (int j = i; j < hi; ++j) atomicAdd(&hist[dst[j] >> BSH], 1);
        }
    }
    __syncthreads();
#pragma unroll
    for (int b = 0; b < NB / 256; ++b) {
        int bb = tid + 256 * b;
        hcnt[(size_t)bb * PBLK + blk] = (unsigned short)hist[bb];
    }
}

// A2a: per-bucket exclusive scan across the PBLK block-counts (in place,
// u16: prefix <= bucket total ~2000) + totals
__global__ __launch_bounds__(256) void k_bscan(unsigned short* __restrict__ hcnt,
                                               int* __restrict__ btot) {
    __shared__ int s[256];
    int b = blockIdx.x, tid = threadIdx.x;
    unsigned short* row = hcnt + (size_t)b * PBLK;
    int a[8];
    int tsum = 0;
#pragma unroll
    for (int j = 0; j < 8; ++j) { a[j] = row[8 * tid + j]; tsum += a[j]; }
    s[tid] = tsum;
    __syncthreads();
    for (int off = 1; off < 256; off <<= 1) {
        int t = (tid >= off) ? s[tid - off] : 0;
        __syncthreads();
        s[tid] += t;
        __syncthreads();
    }
    int ex = s[tid] - tsum;
#pragma unroll
    for (int j = 0; j < 8; ++j) { row[8 * tid + j] = (unsigned short)ex; ex += a[j]; }
    if (tid == 255) btot[b] = s[255];
}

// A3 (bbase folded in): partition edges into buckets; per-block prologue
// re-derives bucket bases from btot via LDS scan; block 0 also writes
// bbase[] (for k_bucket) and rowptr[n]=e. pos from LDS cursor.
// 4 edges/thread: int4 dst + int4 src + float4 ew issued up front.
__global__ __launch_bounds__(256) void k_bpart(const int* __restrict__ src,
                                               const int* __restrict__ dst,
                                               const float* __restrict__ ew,
                                               const unsigned short* __restrict__ hcnt,
                                               const int* __restrict__ btot,
                                               int* __restrict__ bbase,
                                               int* __restrict__ rowptr,
                                               int2* __restrict__ bedge,
                                               int e, int n) {
    __shared__ int cur[NB];
    __shared__ int s[256];
    int tid = threadIdx.x, blk = blockIdx.x;
    // bucket-base scan (old k_bbase, per block; 4 entries/thread)
    int a0 = btot[4 * tid], a1 = btot[4 * tid + 1],
        a2 = btot[4 * tid + 2], a3 = btot[4 * tid + 3];
    int tsum = a0 + a1 + a2 + a3;
    s[tid] = tsum;
    __syncthreads();
    for (int off = 1; off < 256; off <<= 1) {
        int t = (tid >= off) ? s[tid - off] : 0;
        __syncthreads();
        s[tid] += t;
        __syncthreads();
    }
    int ex = s[tid] - tsum;
    int b0 = ex, b1 = ex + a0, b2 = ex + a0 + a1, b3 = ex + a0 + a1 + a2;
    cur[4 * tid + 0] = b0 + hcnt[(size_t)(4 * tid + 0) * PBLK + blk];
    cur[4 * tid + 1] = b1 + hcnt[(size_t)(4 * tid + 1) * PBLK + blk];
    cur[4 * tid + 2] = b2 + hcnt[(size_t)(4 * tid + 2) * PBLK + blk];
    cur[4 * tid + 3] = b3 + hcnt[(size_t)(4 * tid + 3) * PBLK + blk];
    if (blk == 0) {                            // publish bases for k_bucket
        bbase[4 * tid + 0] = b0;
        bbase[4 * tid + 1] = b1;
        bbase[4 * tid + 2] = b2;
        bbase[4 * tid + 3] = b3;
        if (tid == 255) bbase[NB] = s[255];    // == e
        if (tid == 0) rowptr[n] = e;
    }
    __syncthreads();
    int chunk = (((e + PBLK - 1) / PBLK) + 3) & ~3;
    int lo = blk * chunk, hi = min(e, lo + chunk);
    for (int i = lo + tid * 4; i < hi; i += 1024) {
        if (i + 4 <= hi) {
            int4 d4 = *(const int4*)(dst + i);
            int4 s4 = *(const int4*)(src + i);
            float4 w4 = *(const float4*)(ew + i);
            int p0 = atomicAdd(&cur[d4.x >> BSH], 1);
            int p1 = atomicAdd(&cur[d4.y >> BSH], 1);
            int p2 = atomicAdd(&cur[d4.z >> BSH], 1);
            int p3 = atomicAdd(&cur[d4.w >> BSH], 1);
            bedge[p0] = make_int2(s4.x | ((d4.x & BMASK) << 17), __float_as_int(w4.x));
            bedge[p1] = make_int2(s4.y | ((d4.y & BMASK) << 17), __float_as_int(w4.y));
            bedge[p2] = make_int2(s4.z | ((d4.z & BMASK) << 17), __float_as_int(w4.z));
            bedge[p3] = make_int2(s4.w | ((d4.w & BMASK) << 17), __float_as_int(w4.w));
        } else {
            for (int j = i; j < hi; ++j) {
                int d = dst[j];
                int pos = atomicAdd(&cur[d >> BSH], 1);
                bedge[pos] = make_int2(src[j] | ((d & BMASK) << 17),
                                       __float_as_int(ew[j]));
            }
        }
    }
}

// B: per-bucket (BN=128 nodes): LDS packed cnt + fixp sum(ew) -> dis,
// rowptr, then scatter (src, ew*dis[d]) grouped per node into em.
// Fused hs = fp16(dis*x) for this bucket's nodes. No global atomics.
__global__ __launch_bounds__(256) void k_bucket(const int2* __restrict__ bedge,
                                                const int* __restrict__ bbase,
                                                float* __restrict__ dis,
                                                int* __restrict__ rowptr,
                                                int2* __restrict__ em,
                                                const float* __restrict__ x,
                                                __half* __restrict__ hs, int n) {
    __shared__ unsigned long long pk[BN];
    __shared__ int cnt[BN];
    __shared__ int scn[BN];
    __shared__ float sdis[BN];
    __shared__ int cur[BN];
    int b = blockIdx.x, tid = threadIdx.x;
    int e0 = bbase[b], e1 = bbase[b + 1];
    if (tid < BN) pk[tid] = 0ULL;
    __syncthreads();
    for (int i = e0 + tid; i < e1; i += 256) {
        int2 v = bedge[i];
        int dlo = (v.x >> 17) & BMASK;
        unsigned long long p =
            (1ULL << 40) | (unsigned long long)(__int_as_float(v.y) * FIXP_SCALE);
        atomicAdd(&pk[dlo], p);                          // LDS atomic
    }
    __syncthreads();
    if (tid < BN) {
        unsigned long long v = pk[tid];
        int c = (int)(v >> 40);
        cnt[tid] = c; scn[tid] = c;
        sdis[tid] = rsqrtf(1.0f + (float)(v & FIXP_MASK) * (1.0f / FIXP_SCALE));
    }
    __syncthreads();
    // BN-entry inclusive scan (all threads hit the barriers)
    for (int off = 1; off < BN; off <<= 1) {
        int v0 = (tid >= off && tid < BN) ? scn[tid - off] : 0;
        __syncthreads();
        if (tid < BN) scn[tid] += v0;
        __syncthreads();
    }
    if (tid < BN) {
        int rb = e0 + scn[tid] - cnt[tid];               // exclusive
        cur[tid] = rb;
        int node = (b << BSH) + tid;
        if (node < n) { rowptr[node] = rb; dis[node] = sdis[tid]; }
    }
    __syncthreads();
    for (int i = e0 + tid; i < e1; i += 256) {
        int2 v = bedge[i];
        int dlo = (v.x >> 17) & BMASK;
        int pos = atomicAdd(&cur[dlo], 1);               // LDS atomic
        float w = __int_as_float(v.y) * sdis[dlo];
        em[pos] = make_int2(v.x & 0x1FFFF, __float_as_int(w));
    }
    // fused layer-1 pre-scale: hs = fp16(dis * x) for nodes of this bucket
    int nodebase = b << BSH;
    int nloc = n - nodebase; if (nloc > BN) nloc = BN;
    if (nloc > 0) {
        const float2* x2 = (const float2*)(x + (size_t)nodebase * 32);
        __half2* hs2 = (__half2*)(hs + (size_t)nodebase * 32);
        int total2 = nloc * 16;                    // 16 float2 per 32-ch row
        for (int i = tid; i < total2; i += 256) {
            float d = sdis[i >> 4];
            float2 v = x2[i];
            hs2[i] = __float22half2_rn(make_float2(v.x * d, v.y * d));
        }
    }
}

__device__ __forceinline__ v2f cvt2(unsigned int u) {
    __half2 h2 = *(__half2*)&u;
    float2 f = __half22float2(h2);
    v2f r; r.x = f.x; r.y = f.y;
    return r;
}

// R25: pure 32-ch aggregate, 4ch/lane, 16-edge units (2 slots) with
// clean/tail split; 2 NODES PER WAVE; packed v2f accumulate
// (v_pk_fma_f32). y0 = sum_e w_e hs[src] + di*hs[node].
__global__ __launch_bounds__(256, 4) void k_agg32(const __half* __restrict__ hs,
                                                  const int2* __restrict__ em,
                                                  const int* __restrict__ rowptr,
                                                  const float* __restrict__ dis,
                                                  __half* __restrict__ y0, int n) {
    __shared__ __align__(8) int2 sme[4][128];
    int lane = threadIdx.x & 63, wv = threadIdx.x >> 6;
    int c = lane & 7, oct = lane >> 3;
    const uint2* h64 = (const uint2*)hs;      // 8 uint2 per 32-ch row
    int wid = (blockIdx.x * blockDim.x + threadIdx.x) >> 6;
    int n0 = wid * 2;
    if (n0 >= n) return;
    int cnt = min(2, n - n0);
    int rp = 0;
    if (lane <= cnt) rp = rowptr[n0 + lane];
    int hiw = __shfl(rp, cnt, 64);            // end of wave's edge range
    int wlo = 0, whi = 0;                     // staged window [wlo, whi)
    for (int k = 0; k < cnt; ++k) {
        int node = n0 + k;
        int lo = __shfl(rp, k, 64), hi = __shfl(rp, k + 1, 64);
        v2f a0 = {0.0f, 0.0f}, a1 = {0.0f, 0.0f};
        if (oct == 0) {
            float di = dis[node];
            uint2 sh = h64[(unsigned)(node * 8 + c)];
            v2f dv = {di, di};
            a0 = dv * cvt2(sh.x);                        // self: di^2*x = di*hs
            a1 = dv * cvt2(sh.y);
        }
        int idx = lo;
        while (idx < hi) {
            if (idx >= whi) {                 // refill (wave-uniform)
                int i0 = idx + lane;
                if (i0 < hiw) sme[wv][lane] = em[i0];
                int i1 = i0 + 64;
                if (i1 < hiw) sme[wv][lane + 64] = em[i1];
                wlo = idx; whi = idx + 128;
            }
            int base = idx - wlo;
            int take = min(hi, whi) - idx;    // 1..128 edges this pass
            int g = 0;
            // clean 16-edge batches: no predication, no clamped dups
            for (; g + 16 <= take; g += 16) {
                int2 ev[2]; uint2 hv[2];
#pragma unroll
                for (int t = 0; t < 2; ++t)
                    ev[t] = sme[wv][base + g + 8 * t + oct];      // 8-way bcast
#pragma unroll
                for (int t = 0; t < 2; ++t)
                    hv[t] = h64[(unsigned)(ev[t].x * 8 + c)];
#pragma unroll
                for (int t = 0; t < 2; ++t) {
                    float ww = __int_as_float(ev[t].y);
                    v2f wv2 = {ww, ww};
                    a0 += wv2 * cvt2(hv[t].x);           // v_pk_fma_f32
                    a1 += wv2 * cvt2(hv[t].y);
                }
            }
            if (g < take) {                   // predicated tail (<=15 edges)
                int2 ev[2]; uint2 hv[2]; int pr[2];
#pragma unroll
                for (int t = 0; t < 2; ++t) {
                    int p = g + 8 * t + oct;
                    pr[t] = p < take;
                    int pc = pr[t] ? p : 0;               // clamp: stay in window
                    ev[t] = sme[wv][base + pc];
                }
#pragma unroll
                for (int t = 0; t < 2; ++t)
                    hv[t] = h64[(unsigned)(ev[t].x * 8 + c)];
#pragma unroll
                for (int t = 0; t < 2; ++t) {
                    float ww = pr[t] ? __int_as_float(ev[t].y) : 0.0f;
                    v2f wv2 = {ww, ww};
                    a0 += wv2 * cvt2(hv[t].x);
                    a1 += wv2 * cvt2(hv[t].y);
                }
            }
            idx += take;
        }
        // reduce across octs
        a0.x += __shfl_down(a0.x, 32, 64); a0.y += __shfl_down(a0.y, 32, 64);
        a1.x += __shfl_down(a1.x, 32, 64); a1.y += __shfl_down(a1.y, 32, 64);
        a0.x += __shfl_down(a0.x, 16, 64); a0.y += __shfl_down(a0.y, 16, 64);
        a1.x += __shfl_down(a1.x, 16, 64); a1.y += __shfl_down(a1.y, 16, 64);
        a0.x += __shfl_down(a0.x, 8, 64);  a0.y += __shfl_down(a0.y, 8, 64);
        a1.x += __shfl_down(a1.x, 8, 64);  a1.y += __shfl_down(a1.y, 8, 64);
        if (oct == 0) {
            uint2 o;
            __half2 p0 = __float22half2_rn(make_float2(a0.x, a0.y));
            __half2 p1 = __float22half2_rn(make_float2(a1.x, a1.y));
            o.x = *(unsigned int*)&p0; o.y = *(unsigned int*)&p1;
            ((uint2*)y0)[(size_t)node * 8 + c] = o;
        }
    }
}

// R22: h1' = silu(y0 @ W1 + b1) * dis.  4 THREADS PER NODE (q = 16
// outputs each); o[16], ~35 live regs (lottery-proof), grid 1563.
__global__ __launch_bounds__(256, 4) void k_mm32act(const __half* __restrict__ y0,
                                                    const float* __restrict__ W,
                                                    const float* __restrict__ bias,
                                                    const float* __restrict__ dis,
                                                    __half* __restrict__ out, int n) {
    __shared__ __align__(16) float sw[32 * 64 + 64];
#pragma unroll
    for (int i = 0; i < 8; ++i)
        sw[threadIdx.x + 256 * i] = W[threadIdx.x + 256 * i];
    if (threadIdx.x < 64) sw[2048 + threadIdx.x] = bias[threadIdx.x];
    __syncthreads();
    int idx = blockIdx.x * 256 + threadIdx.x;
    int node = idx >> 2, q = idx & 3;
    if (node >= n) return;
    const uint4* yrow = (const uint4*)(y0 + (size_t)node * 32);
    float o[16];
#pragma unroll
    for (int j = 0; j < 16; ++j) o[j] = sw[2048 + q * 16 + j];
#pragma unroll
    for (int kb = 0; kb < 2; ++kb) {           // 2 chunks of 16 channels
        uint4 ya = yrow[2 * kb], yb = yrow[2 * kb + 1];
        unsigned int yw[8] = {ya.x, ya.y, ya.z, ya.w, yb.x, yb.y, yb.z, yb.w};
#pragma unroll
        for (int k2 = 0; k2 < 8; ++k2) {
            float2 yk = __half22float2(*(__half2*)&yw[k2]);
            int k = kb * 16 + 2 * k2;
            const float4* r0 = (const float4*)&sw[k * 64 + q * 16];
            const float4* r1 = (const float4*)&sw[(k + 1) * 64 + q * 16];
#pragma unroll
            for (int j4 = 0; j4 < 4; ++j4) {
                float4 w0 = r0[j4];
                float4 w1 = r1[j4];
                o[4 * j4 + 0] = fmaf(yk.y, w1.x, fmaf(yk.x, w0.x, o[4 * j4 + 0]));
                o[4 * j4 + 1] = fmaf(yk.y, w1.y, fmaf(yk.x, w0.y, o[4 * j4 + 1]));
                o[4 * j4 + 2] = fmaf(yk.y, w1.z, fmaf(yk.x, w0.z, o[4 * j4 + 2]));
                o[4 * j4 + 3] = fmaf(yk.y, w1.w, fmaf(yk.x, w0.w, o[4 * j4 + 3]));
            }
        }
    }
    float dsc = dis[node];
    __half2* orow = (__half2*)(out + (size_t)node * 64 + q * 16);
#pragma unroll
    for (int j2 = 0; j2 < 8; ++j2) {
        float ox = o[2 * j2], oy = o[2 * j2 + 1];
        ox = ox / (1.0f + __expf(-ox)) * dsc;
        oy = oy / (1.0f + __expf(-oy)) * dsc;
        orow[j2] = __float22half2_rn(make_float2(ox, oy));
    }
}

// R22: z = y @ W  (N x 64 fp16 in, 64x64 fp32 W in LDS, N x 64 fp16 out).
// 4 THREADS PER NODE (q = 16 outputs each); o[16], grid 1563.
__global__ __launch_bounds__(256, 4) void k_mm64(const __half* __restrict__ y,
                                                 const float* __restrict__ W,
                                                 __half* __restrict__ z, int n) {
    __shared__ __align__(16) float sw[64 * 64];     // 16 KB
#pragma unroll
    for (int i = 0; i < 16; ++i)
        sw[threadIdx.x + 256 * i] = W[threadIdx.x + 256 * i];
    __syncthreads();
    int idx = blockIdx.x * 256 + threadIdx.x;
    int node = idx >> 2, q = idx & 3;
    if (node >= n) return;
    const uint4* yrow = (const uint4*)(y + (size_t)node * 64);
    float o[16];
#pragma unroll
    for (int j = 0; j < 16; ++j) o[j] = 0.0f;
#pragma unroll
    for (int kb = 0; kb < 4; ++kb) {           // 4 chunks of 16 channels
        uint4 ya = yrow[2 * kb], yb = yrow[2 * kb + 1];
        unsigned int yw[8] = {ya.x, ya.y, ya.z, ya.w, yb.x, yb.y, yb.z, yb.w};
#pragma unroll
        for (int k2 = 0; k2 < 8; ++k2) {
            float2 yk = __half22float2(*(__half2*)&yw[k2]);
            int k = kb * 16 + 2 * k2;
            const float4* r0 = (const float4*)&sw[k * 64 + q * 16];
            const float4* r1 = (const float4*)&sw[(k + 1) * 64 + q * 16];
#pragma unroll
            for (int j4 = 0; j4 < 4; ++j4) {
                float4 w0 = r0[j4];
                float4 w1 = r1[j4];
                o[4 * j4 + 0] = fmaf(yk.y, w1.x, fmaf(yk.x, w0.x, o[4 * j4 + 0]));
                o[4 * j4 + 1] = fmaf(yk.y, w1.y, fmaf(yk.x, w0.y, o[4 * j4 + 1]));
                o[4 * j4 + 2] = fmaf(yk.y, w1.z, fmaf(yk.x, w0.z, o[4 * j4 + 2]));
                o[4 * j4 + 3] = fmaf(yk.y, w1.w, fmaf(yk.x, w0.w, o[4 * j4 + 3]));
            }
        }
    }
    __half2* zrow = (__half2*)(z + (size_t)node * 64 + q * 16);
#pragma unroll
    for (int j2 = 0; j2 < 8; ++j2)
        zrow[j2] = __float22half2_rn(make_float2(o[2 * j2], o[2 * j2 + 1]));
}

// R25: lean 64-ch aggregate, 4ch/lane, 16-edge units (4 slots) with
// clean/tail split; 2 NODES PER WAVE; packed v2f accumulate
// (v_pk_fma_f32). out = [di*] silu( sum_e w_e z[src] + di*z[node] + b ).
template <bool SCALE, typename OUT>
__global__ __launch_bounds__(256, 4) void k_agg64(const __half* __restrict__ z,
                                                  const int2* __restrict__ em,
                                                  const int* __restrict__ rowptr,
                                                  const float* __restrict__ dis,
                                                  const float* __restrict__ bias,
                                                  OUT* __restrict__ out, int n) {
    __shared__ __align__(8) int2 sme[4][128];
    int lane = threadIdx.x & 63, wv = threadIdx.x >> 6;
    int c = lane & 15, quarter = lane >> 4;
    const uint2* h64 = (const uint2*)z;       // 16 uint2 per 64-ch row
    float4 bv4 = ((const float4*)bias)[c];
    int wid = (blockIdx.x * blockDim.x + threadIdx.x) >> 6;
    int n0 = wid * 2;
    if (n0 >= n) return;
    int cnt = min(2, n - n0);
    int rp = 0;
    if (lane <= cnt) rp = rowptr[n0 + lane];
    int hiw = __shfl(rp, cnt, 64);
    int wlo = 0, whi = 0;
    for (int k = 0; k < cnt; ++k) {
        int node = n0 + k;
        int lo = __shfl(rp, k, 64), hi = __shfl(rp, k + 1, 64);
        float di = 0.0f;
        v2f a0 = {0.0f, 0.0f}, a1 = {0.0f, 0.0f};
        if (quarter == 0) {
            di = dis[node];
            uint2 sh = h64[(unsigned)(node * 16 + c)];
            v2f dv = {di, di};
            a0 = dv * cvt2(sh.x);                        // self-loop term
            a1 = dv * cvt2(sh.y);
        }
        int idx = lo;
        while (idx < hi) {
            if (idx >= whi) {                 // refill (wave-uniform)
                int i0 = idx + lane;
                if (i0 < hiw) sme[wv][lane] = em[i0];
                int i1 = i0 + 64;
                if (i1 < hiw) sme[wv][lane + 64] = em[i1];
                wlo = idx; whi = idx + 128;
            }
            int base = idx - wlo;
            int take = min(hi, whi) - idx;
            int g = 0;
            // clean 16-edge batches: no predication, no clamped dups
            for (; g + 16 <= take; g += 16) {
                int2 ev[4]; uint2 hv[4];
#pragma unroll
                for (int t = 0; t < 4; ++t)
                    ev[t] = sme[wv][base + g + 4 * t + quarter];  // 4-way bcast
#pragma unroll
                for (int t = 0; t < 4; ++t)
                    hv[t] = h64[(unsigned)(ev[t].x * 16 + c)];
#pragma unroll
                for (int t = 0; t < 4; ++t) {
                    float ww = __int_as_float(ev[t].y);
                    v2f wv2 = {ww, ww};
                    a0 += wv2 * cvt2(hv[t].x);           // v_pk_fma_f32
                    a1 += wv2 * cvt2(hv[t].y);
                }
            }
            if (g < take) {                   // predicated tail (<=15 edges)
                int2 ev[4]; uint2 hv[4]; int pr[4];
#pragma unroll
                for (int t = 0; t < 4; ++t) {
                    int p = g + 4 * t + quarter;
                    pr[t] = p < take;
                    int pc = pr[t] ? p : 0;               // clamp: stay in window
                    ev[t] = sme[wv][base + pc];
                }
#pragma unroll
                for (int t = 0; t < 4; ++t)
                    hv[t] = h64[(unsigned)(ev[t].x * 16 + c)];
#pragma unroll
                for (int t = 0; t < 4; ++t) {
                    float ww = pr[t] ? __int_as_float(ev[t].y) : 0.0f;
                    v2f wv2 = {ww, ww};
                    a0 += wv2 * cvt2(hv[t].x);
                    a1 += wv2 * cvt2(hv[t].y);
                }
            }
            idx += take;
        }
        a0.x += __shfl_down(a0.x, 32, 64); a0.y += __shfl_down(a0.y, 32, 64);
        a1.x += __shfl_down(a1.x, 32, 64); a1.y += __shfl_down(a1.y, 32, 64);
        a0.x += __shfl_down(a0.x, 16, 64); a0.y += __shfl_down(a0.y, 16, 64);
        a1.x += __shfl_down(a1.x, 16, 64); a1.y += __shfl_down(a1.y, 16, 64);
        if (quarter == 0) {
            float ox = a0.x + bv4.x, oy = a0.y + bv4.y;
            float oz = a1.x + bv4.z, ow = a1.y + bv4.w;
            ox = ox / (1.0f + __expf(-ox));
            oy = oy / (1.0f + __expf(-oy));
            oz = oz / (1.0f + __expf(-oz));
            ow = ow / (1.0f + __expf(-ow));
            if (SCALE) { ox *= di; oy *= di; oz *= di; ow *= di; }
            if (sizeof(OUT) == 2) {
                uint2 o;
                __half2 p0 = __float22half2_rn(make_float2(ox, oy));
                __half2 p1 = __float22half2_rn(make_float2(oz, ow));
                o.x = *(unsigned int*)&p0; o.y = *(unsigned int*)&p1;
                ((uint2*)out)[(size_t)node * 16 + c] = o;
            } else {
                ((float4*)out)[(size_t)node * 16 + c] = make_float4(ox, oy, oz, ow);
            }
        }
    }
}

// pool phase 1 (fp16 input): 128-row chunks, segment-flush atomics
__global__ void k_pool_partial(const __half* __restrict__ h, const int* __restrict__ batch,
                               float* __restrict__ acc, int n) {
    int c = threadIdx.x & 63, r = threadIdx.x >> 6;
    int base = blockIdx.x * 128;
    int end = base + 128; if (end > n) end = n;
    float part = 0.0f;
    int cur = -1;
    for (int i = base + r; i < end; i += 4) {
        int g = batch[i];
        if (g != cur) {
            if (cur >= 0) atomicAdd(&acc[cur * 64 + c], part);
            part = 0.0f;
            cur = g;
        }
        part += __half2float(h[(size_t)i * 64 + c]);
    }
    if (cur >= 0) atomicAdd(&acc[cur * 64 + c], part);
}

// pool phase 2: divide by per-graph count
__global__ void k_pool_final(const float* __restrict__ acc, const int* __restrict__ batch,
                             float* __restrict__ out, int n) {
    int idx = blockIdx.x * blockDim.x + threadIdx.x;   // G*64 threads
    int g = idx >> 6;
    int lo = lower_bound_i(batch, n, g);
    int hi = lower_bound_i(batch, n, g + 1);
    int cnt = hi - lo;
    out[idx] = acc[idx] / (float)(cnt > 0 ? cnt : 1);
}

extern "C" void kernel_launch(void* const* d_in, const int* in_sizes, int n_in,
                              void* d_out, int out_size, void* d_ws, size_t ws_size,
                              hipStream_t stream) {
    const float* x   = (const float*)d_in[0];
    const float* ew  = (const float*)d_in[1];
    const float* W1  = (const float*)d_in[2];
    const float* b1  = (const float*)d_in[3];
    const float* W2  = (const float*)d_in[4];
    const float* b2  = (const float*)d_in[5];
    const float* W3  = (const float*)d_in[6];
    const float* b3  = (const float*)d_in[7];
    const int*   eidx  = (const int*)d_in[8];
    const int*   batch = (const int*)d_in[9];
    float* out = (float*)d_out;

    const int E = in_sizes[1];       // 1,600,000
    const int N = in_sizes[9];       // 100,000 (< 131072: fits 17-bit src pack)
    const int G = 64;
    const int* src = eidx;
    const int* dst = eidx + E;

    // workspace: A/B (fp16 features) double as CSR-build scratch
    // (bedge in A: E*8B == N*64*2B exactly; hcnt(u16 4MB)+btot in B);
    // C holds fp16 y0 early; layer-3 out is fp16 into A (dead there).
    char* p = (char*)d_ws;
    __half* A     = (__half*)p;                p += (size_t)N * 64 * sizeof(__half);
    __half* B     = (__half*)p;                p += (size_t)N * 64 * sizeof(__half);
    float* C      = (float*)p;                 p += (size_t)N * 64 * sizeof(float);
    float* dis    = (float*)p;                 p += (size_t)N * sizeof(float);
    int*   rowptr = (int*)p;                   p += (size_t)(N + 1) * sizeof(int);
    int*   bbase  = (int*)p;                   p += (size_t)(NB + 1) * sizeof(int);
    float* acc    = (float*)p;                 p += (size_t)G * 64 * sizeof(float);
    p = (char*)(((uintptr_t)p + 7) & ~(uintptr_t)7);
    int2*  em     = (int2*)p;                  // E entries, 8B

    int2* bedge = (int2*)A;                    // E*8B == N*64*2B
    unsigned short* hcnt = (unsigned short*)B; // NB*PBLK*2B = 4MB
    int*  btot  = (int*)((char*)B + (size_t)NB * PBLK * 2);  // NB ints

    const int BT = 256;
    const int WAVES = (N + 1) / 2;             // 50000 waves, 2 contiguous nodes each
    const int AGG_BLOCKS = (WAVES + 3) / 4;    // 12500
    const int MM_BLOCKS = (4 * N + 255) / 256; // 1563, 4 threads per node

    // --- CSR build: LDS counting sort, zero global atomics ---
    k_bhist<<<PBLK, 256, 0, stream>>>(dst, hcnt, E);
    k_bscan<<<NB, 256, 0, stream>>>(hcnt, btot);
    // bbase folded into k_bpart (block 0 publishes bbase + rowptr[n])
    k_bpart<<<PBLK, 256, 0, stream>>>(src, dst, ew, hcnt, btot, bbase, rowptr,
                                      bedge, E, N);
    // k_bucket also emits hs = fp16(dis*x) into B (hcnt scratch dead here)
    k_bucket<<<NB, 256, 0, stream>>>(bedge, bbase, dis, rowptr, em, x, (__half*)B, N);

    // --- layer 1: pure 32-ch aggregate -> y0 (fp16, in C) ;
    //     h1' = silu(y0@W1+b1)*dis -> A ---
    k_agg32<<<AGG_BLOCKS, BT, 0, stream>>>((__half*)B, em, rowptr, dis, (__half*)C, N);
    k_mm32act<<<MM_BLOCKS, BT, 0, stream>>>((__half*)C, W1, b1, dis, A, N);

    // --- layer 2: z2 = y1 @ W2 -> B ; agg+bias+silu*dis -> A ---
    k_mm64<<<MM_BLOCKS, BT, 0, stream>>>(A, W2, B, N);
    k_agg64<true, __half><<<AGG_BLOCKS, BT, 0, stream>>>(B, em, rowptr, dis, b2, A, N);

    // --- layer 3: z3 = y2 @ W3 -> B ; agg+bias+silu (fp16) -> A ---
    k_mm64<<<MM_BLOCKS, BT, 0, stream>>>(A, W3, B, N);
    k_agg64<false, __half><<<AGG_BLOCKS, BT, 0, stream>>>(B, em, rowptr, dis, b3, A, N);

    // --- mean pool (fp16 input) ---
    hipMemsetAsync(acc, 0, (size_t)G * 64 * sizeof(float), stream);
    k_pool_partial<<<(N + 127) / 128, BT, 0, stream>>>(A, batch, acc, N);
    k_pool_final<<<(G * 64) / BT, BT, 0, stream>>>(acc, batch, out, N);
}